// Round 1
// baseline (1317.915 us; speedup 1.0000x reference)
//
#include <hip/hip_runtime.h>
#include <math.h>

// ---------------------------------------------------------------------------
// VQ-VAE encoder, fp32. B=64, Cin=64, T=4096; h=128, rh=64, D=64, K=512.
// Conv chain -> combined 1x1 -> z_e (B,1024,64) -> VQ (argmin over 512 codes).
// All compute fp32 (no fp32 MFMA on CDNA4; argmin gaps too tight for bf16).
// ---------------------------------------------------------------------------

template<int CIN, int COUT, int K, int S, int TP,
         bool RELU_IN, bool RELU_OUT, bool HAS_BIAS, bool ACCUM, bool TRANSPOSED>
__global__ __launch_bounds__(256) void conv_k(
    const float* __restrict__ in, const float* __restrict__ w,
    const float* __restrict__ bias, float* __restrict__ out,
    int Tin, int Tout)
{
  constexpr int CC   = 16;                 // ci chunk staged in LDS
  constexpr int TT   = 64 * TP;            // t-tile (lane = t, TP positions/thread)
  constexpr int PADL = (K == 1) ? 0 : 1;
  constexpr int SPAN = S * (TT - 1) + K;   // input halo span
  constexpr int XSP  = SPAN + 2;
  constexpr int KP   = (K >= 3) ? 4 : K;   // padded k-stride for aligned float4
  constexpr int CO_PER = COUT / 4;         // co per thread (4 waves)

  static_assert(!TRANSPOSED || COUT == 64, "transpose path assumes COUT==64");

  __shared__ __align__(16) float xs[CC * XSP];
  __shared__ __align__(16) float wsm[CC * COUT * KP];
  __shared__ float ts[TRANSPOSED ? (TT * 65) : 1];

  const int b    = blockIdx.y;
  const int t0   = blockIdx.x * TT;
  const int tid  = threadIdx.x;
  const int lane = tid & 63;
  const int wv   = tid >> 6;

  float acc[CO_PER][TP];
  #pragma unroll
  for (int c = 0; c < CO_PER; c++)
    #pragma unroll
    for (int u = 0; u < TP; u++) acc[c][u] = 0.f;

  const int in_b = S * t0 - PADL;

  for (int c0 = 0; c0 < CIN; c0 += CC) {
    __syncthreads();
    // stage x tile (with zero halo, optional input relu)
    for (int i = tid; i < CC * SPAN; i += 256) {
      int ci = i / SPAN;
      int j  = i - ci * SPAN;
      int tin = in_b + j;
      float v = 0.f;
      if (tin >= 0 && tin < Tin)
        v = in[(size_t)(b * CIN + c0 + ci) * Tin + tin];
      if (RELU_IN) v = fmaxf(v, 0.f);
      xs[ci * XSP + j] = v;
    }
    // stage weights: global (co,ci,k) -> LDS [ci][co*KP+k]
    for (int i = tid; i < COUT * CC * K; i += 256) {
      int co = i / (CC * K);
      int r  = i - co * (CC * K);
      int ci = r / K;
      int k  = r - ci * K;
      wsm[ci * (COUT * KP) + co * KP + k] = w[(size_t)co * (CIN * K) + c0 * K + r];
    }
    __syncthreads();

    for (int ci = 0; ci < CC; ci++) {
      float xv[TP][K];
      #pragma unroll
      for (int u = 0; u < TP; u++)
        #pragma unroll
        for (int k = 0; k < K; k++)
          xv[u][k] = xs[ci * XSP + S * (lane + 64 * u) + k];
      const float* wr = &wsm[ci * (COUT * KP) + wv * (CO_PER * KP)];
      if constexpr (K == 1) {
        #pragma unroll
        for (int cq = 0; cq < CO_PER / 4; cq++) {
          float4 wc = *(const float4*)(wr + cq * 4);   // wave-uniform broadcast
          #pragma unroll
          for (int u = 0; u < TP; u++) {
            acc[cq*4+0][u] = fmaf(xv[u][0], wc.x, acc[cq*4+0][u]);
            acc[cq*4+1][u] = fmaf(xv[u][0], wc.y, acc[cq*4+1][u]);
            acc[cq*4+2][u] = fmaf(xv[u][0], wc.z, acc[cq*4+2][u]);
            acc[cq*4+3][u] = fmaf(xv[u][0], wc.w, acc[cq*4+3][u]);
          }
        }
      } else {
        #pragma unroll
        for (int cg = 0; cg < CO_PER; cg++) {
          float4 wc = *(const float4*)(wr + cg * KP);  // wave-uniform broadcast
          #pragma unroll
          for (int u = 0; u < TP; u++) {
            float a = acc[cg][u];
            a = fmaf(xv[u][0], wc.x, a);
            a = fmaf(xv[u][1], wc.y, a);
            a = fmaf(xv[u][2], wc.z, a);
            if constexpr (K == 4) a = fmaf(xv[u][3], wc.w, a);
            acc[cg][u] = a;
          }
        }
      }
    }
  }

  if constexpr (!TRANSPOSED) {
    #pragma unroll
    for (int cg = 0; cg < CO_PER; cg++) {
      int co = wv * CO_PER + cg;
      float bs = 0.f;
      if constexpr (HAS_BIAS) bs = bias[co];
      #pragma unroll
      for (int u = 0; u < TP; u++) {
        int t = t0 + lane + 64 * u;
        float v = acc[cg][u] + bs;
        if (RELU_OUT) v = fmaxf(v, 0.f);
        size_t oi = (size_t)(b * COUT + co) * Tout + t;
        if constexpr (ACCUM) out[oi] += v;
        else out[oi] = v;
      }
    }
  } else {
    // write z in (b, t, d) layout via LDS transpose, coalesced dword stores
    __syncthreads();
    #pragma unroll
    for (int cg = 0; cg < CO_PER; cg++) {
      int co = wv * CO_PER + cg;
      float bs = HAS_BIAS ? bias[co] : 0.f;
      #pragma unroll
      for (int u = 0; u < TP; u++)
        ts[(lane + 64 * u) * 65 + co] = acc[cg][u] + bs;
    }
    __syncthreads();
    const size_t base = ((size_t)b * Tout + t0) * COUT;
    for (int i = tid; i < TT * COUT; i += 256) {
      int tl = i >> 6;
      int co = i & 63;
      out[base + i] = ts[tl * 65 + co];
    }
  }
}

// ---- prep: Wc = wpq @ w_out, bc = wpq @ b_out + bpq, cnorm[k] = |c_k|^2 ----
__global__ __launch_bounds__(256) void prep_k(
    const float* __restrict__ w_out, const float* __restrict__ b_out,
    const float* __restrict__ wpq, const float* __restrict__ bpq,
    const float* __restrict__ cb,
    float* __restrict__ Wc, float* __restrict__ bc, float* __restrict__ cnorm)
{
  const int tid = threadIdx.x;
  for (int i = tid; i < 64 * 128; i += 256) {
    int d = i >> 7, c = i & 127;
    float s = 0.f;
    for (int e = 0; e < 64; e++) s = fmaf(wpq[d * 64 + e], w_out[e * 128 + c], s);
    Wc[i] = s;
  }
  for (int i = tid; i < 64; i += 256) {
    float s = bpq[i];
    for (int e = 0; e < 64; e++) s = fmaf(wpq[i * 64 + e], b_out[e], s);
    bc[i] = s;
  }
  for (int k = tid; k < 512; k += 256) {
    float s = 0.f;
    for (int d = 0; d < 64; d++) { float c = cb[k * 64 + d]; s = fmaf(c, c, s); }
    cnorm[k] = s;
  }
}

// ---- VQ: 64 points/block, z in regs, codebook chunks broadcast from LDS ----
__global__ __launch_bounds__(256) void vq_k(
    const float* __restrict__ ze,        // (N,64)
    const float* __restrict__ cb,        // (512,64)
    const float* __restrict__ cnorm,     // (512)
    float* __restrict__ zq_out,          // (N,64)
    float* __restrict__ enc,             // (N,512), pre-zeroed
    float* __restrict__ idx_out,         // (N)
    int* __restrict__ counts, float* __restrict__ loss_accum)
{
  __shared__ __align__(16) float cs[64 * 64];
  __shared__ float cns[64];
  __shared__ float red_v[4 * 64];
  __shared__ int   red_i[4 * 64];
  __shared__ int   idx_s[64];
  __shared__ float ls[4];

  const int tid  = threadIdx.x;
  const int lane = tid & 63;
  const int wv   = tid >> 6;
  const int n0   = blockIdx.x * 64;

  // this lane's z point in registers (ze base is 8B-aligned: use float2)
  float zr[64];
  const float* zp = ze + (size_t)(n0 + lane) * 64;
  #pragma unroll
  for (int j = 0; j < 32; j++) {
    float2 v = *(const float2*)(zp + 2 * j);
    zr[2 * j] = v.x; zr[2 * j + 1] = v.y;
  }

  float best = 3.4e38f;
  int   bidx = 0;

  for (int ch = 0; ch < 8; ch++) {
    __syncthreads();
    for (int i = tid; i < 4096; i += 256) cs[i] = cb[ch * 4096 + i];
    if (tid < 64) cns[tid] = cnorm[ch * 64 + tid];
    __syncthreads();
    #pragma unroll
    for (int cg = 0; cg < 16; cg++) {
      int cl = wv * 16 + cg;
      const float* crow = &cs[cl * 64];
      float s0 = 0.f, s1 = 0.f, s2 = 0.f, s3 = 0.f;
      #pragma unroll
      for (int d = 0; d < 64; d += 4) {
        float4 cv = *(const float4*)(crow + d);      // broadcast
        s0 = fmaf(cv.x, zr[d],     s0);
        s1 = fmaf(cv.y, zr[d + 1], s1);
        s2 = fmaf(cv.z, zr[d + 2], s2);
        s3 = fmaf(cv.w, zr[d + 3], s3);
      }
      float dot  = (s0 + s1) + (s2 + s3);
      float dist = cns[cl] - 2.f * dot;              // |z|^2 const per row: drop
      int c = ch * 64 + cl;
      if (dist < best) { best = dist; bidx = c; }    // strict <: keeps lowest idx
    }
  }

  // cross-wave argmin per point (waves cover disjoint code sets)
  red_v[wv * 64 + lane] = best;
  red_i[wv * 64 + lane] = bidx;
  __syncthreads();
  if (wv == 0) {
    float bv = red_v[lane]; int bi = red_i[lane];
    #pragma unroll
    for (int w = 1; w < 4; w++) {
      float v = red_v[w * 64 + lane]; int i2 = red_i[w * 64 + lane];
      if (v < bv || (v == bv && i2 < bi)) { bv = v; bi = i2; }
    }
    idx_s[lane] = bi;
    idx_out[n0 + lane] = (float)bi;
    atomicAdd(&counts[bi], 1);
    enc[(size_t)(n0 + lane) * 512 + bi] = 1.0f;
  }
  __syncthreads();

  // z_q gather + loss, linear coalesced pass over the 64x64 tile
  float lsum = 0.f;
  const size_t obase = (size_t)n0 * 64;
  #pragma unroll
  for (int j = 0; j < 16; j++) {
    int pos = j * 256 + tid;
    int p = pos >> 6, d = pos & 63;
    int id = idx_s[p];                       // wave-uniform
    float zq  = cb[id * 64 + d];             // coalesced row read (L2-hot)
    float zev = ze[obase + pos];
    float df  = zq - zev;
    lsum = fmaf(df, df, lsum);
    zq_out[obase + pos] = zq;                // z_q_st == z_q in forward value
  }
  #pragma unroll
  for (int off = 32; off; off >>= 1) lsum += __shfl_down(lsum, off, 64);
  if (lane == 0) ls[wv] = lsum;
  __syncthreads();
  if (tid == 0) atomicAdd(loss_accum, ls[0] + ls[1] + ls[2] + ls[3]);
}

// ---- finalize: loss scale + perplexity from histogram ----
__global__ __launch_bounds__(256) void fin_k(
    const int* __restrict__ counts, const float* __restrict__ loss_accum,
    float* __restrict__ loss_out, float* __restrict__ perp_out)
{
  __shared__ float sd[256];
  const int tid = threadIdx.x;
  float h = 0.f;
  for (int k = tid; k < 512; k += 256) {
    float em = (float)counts[k] * (1.0f / 65536.0f);
    h += em * logf(em + 1e-10f);
  }
  sd[tid] = h;
  __syncthreads();
  for (int s = 128; s; s >>= 1) {
    if (tid < s) sd[tid] += sd[tid + s];
    __syncthreads();
  }
  if (tid == 0) {
    *perp_out = expf(-sd[0]);
    *loss_out = *loss_accum * 1.25f / 4194304.f;   // (1+BETA)*mean over B*Tq*D
  }
}

extern "C" void kernel_launch(void* const* d_in, const int* in_sizes, int n_in,
                              void* d_out, int out_size, void* d_ws, size_t ws_size,
                              hipStream_t stream)
{
  const float* x    = (const float*)d_in[0];
  const float* w1   = (const float*)d_in[1];
  const float* b1   = (const float*)d_in[2];
  const float* w2   = (const float*)d_in[3];
  const float* b2   = (const float*)d_in[4];
  const float* w3   = (const float*)d_in[5];
  const float* b3   = (const float*)d_in[6];
  const float* r0a  = (const float*)d_in[7];
  const float* r0b  = (const float*)d_in[8];
  const float* r1a  = (const float*)d_in[9];
  const float* r1b  = (const float*)d_in[10];
  const float* wout = (const float*)d_in[11];
  const float* bout = (const float*)d_in[12];
  const float* wpq  = (const float*)d_in[13];
  const float* bpq  = (const float*)d_in[14];
  const float* cb   = (const float*)d_in[15];

  float* out  = (float*)d_out;
  char*  ws   = (char*)d_ws;
  float* buf0 = (float*)(ws);                         // 33.5 MB: h1 -> h3
  float* buf1 = (float*)(ws + 33554432);              // 33.5 MB: h2 -> res tmp
  char*  sm   = ws + 67108864;
  float* Wc     = (float*)(sm);                       // 64x128
  float* bc     = (float*)(sm + 32768);               // 64
  float* cnorm  = (float*)(sm + 33024);               // 512
  int*   counts = (int*)  (sm + 35072);               // 512
  float* lossa  = (float*)(sm + 37120);               // 1

  // output layout (floats): loss | z_q_st (4194304) | perp | z_e (4194304)
  //                         | encodings (33554432) | indices (65536)
  float* loss_out = out;
  float* zq_out   = out + 1;
  float* perp_out = out + 4194305;
  float* ze_out   = out + 4194306;
  float* enc_out  = out + 8388610;
  float* idx_out  = out + 41943042;

  prep_k<<<dim3(1), dim3(256), 0, stream>>>(wout, bout, wpq, bpq, cb, Wc, bc, cnorm);
  hipMemsetAsync(counts, 0, 2052, stream);
  hipMemsetAsync(enc_out, 0, (size_t)33554432 * 4, stream);

  // conv1: 64->64, K4 S2, relu           (B,64,4096) -> (B,64,2048)
  conv_k<64,64,4,2,2,  false,true, true, false,false>
      <<<dim3(16,64), dim3(256), 0, stream>>>(x,    w1, b1, buf0, 4096, 2048);
  // conv2: 64->128, K4 S2, relu          -> (B,128,1024)
  conv_k<64,128,4,2,2, false,true, true, false,false>
      <<<dim3(8,64), dim3(256), 0, stream>>>(buf0, w2, b2, buf1, 2048, 1024);
  // conv3: 128->128, K3 S1, bias only    -> (B,128,1024)
  conv_k<128,128,3,1,2,false,false,true, false,false>
      <<<dim3(8,64), dim3(256), 0, stream>>>(buf1, w3, b3, buf0, 1024, 1024);
  // res block 0
  conv_k<128,64,3,1,2, true, true, false,false,false>
      <<<dim3(8,64), dim3(256), 0, stream>>>(buf0, r0a, nullptr, buf1, 1024, 1024);
  conv_k<64,128,1,1,2, false,false,false,true, false>
      <<<dim3(8,64), dim3(256), 0, stream>>>(buf1, r0b, nullptr, buf0, 1024, 1024);
  // res block 1
  conv_k<128,64,3,1,2, true, true, false,false,false>
      <<<dim3(8,64), dim3(256), 0, stream>>>(buf0, r1a, nullptr, buf1, 1024, 1024);
  conv_k<64,128,1,1,2, false,false,false,true, false>
      <<<dim3(8,64), dim3(256), 0, stream>>>(buf1, r1b, nullptr, buf0, 1024, 1024);
  // final: relu + combined (wpq @ w_out) 1x1, writes z_e in (B,T,D)
  conv_k<128,64,1,1,2, true, false,true, false,true >
      <<<dim3(8,64), dim3(256), 0, stream>>>(buf0, Wc, bc, ze_out, 1024, 1024);

  vq_k<<<dim3(1024), dim3(256), 0, stream>>>(ze_out, cb, cnorm, zq_out, enc_out,
                                             idx_out, counts, lossa);
  fin_k<<<dim3(1), dim3(256), 0, stream>>>(counts, lossa, loss_out, perp_out);
}

// Round 2
// 1051.272 us; speedup vs baseline: 1.2536x; 1.2536x over previous
//
#include <hip/hip_runtime.h>
#include <math.h>

// ---------------------------------------------------------------------------
// VQ-VAE encoder, fp32. B=64, Cin=64, T=4096; h=128, rh=64, D=64, K=512.
// Round 2: wave-uniform weights/codebook via scalar (SMEM) loads instead of
// LDS broadcast (LDS unit is per-CU and was 4x oversubscribed). LDS keeps
// only the x tile. VQ register-blocks 2 points/lane and fuses the encodings
// one-hot write (no more 134 MB memset).
// ---------------------------------------------------------------------------

template<int CIN, int COUT, int K, int S, int TP,
         bool RELU_IN, bool RELU_OUT, bool HAS_BIAS, bool ACCUM, bool TRANSPOSED>
__global__ __launch_bounds__(256) void conv_k(
    const float* __restrict__ in, const float* __restrict__ wT,
    const float* __restrict__ bias, float* __restrict__ out,
    int Tin, int Tout)
{
  constexpr int CC   = 32;                 // ci chunk staged in LDS
  constexpr int TT   = 64 * TP;            // t-tile (lane = t, TP positions)
  constexpr int PADL = (K == 1) ? 0 : 1;
  constexpr int SPAN = S * (TT - 1) + K;
  constexpr int XSP  = SPAN + 2;
  constexpr int KP   = (K == 1) ? 1 : 4;   // padded k-stride (float4 aligned)
  constexpr int CO_PER = COUT / 4;         // co per wave (4 waves)

  static_assert(!TRANSPOSED || COUT == 64, "transpose path assumes COUT==64");

  __shared__ __align__(16) float xs[CC * XSP];
  __shared__ float ts[TRANSPOSED ? (TT * 65) : 1];

  const int b    = blockIdx.y;
  const int t0   = blockIdx.x * TT;
  const int tid  = threadIdx.x;
  const int lane = tid & 63;
  const int wvu  = __builtin_amdgcn_readfirstlane(tid >> 6);  // SGPR wave id

  float acc[CO_PER][TP];
  #pragma unroll
  for (int c = 0; c < CO_PER; c++)
    #pragma unroll
    for (int u = 0; u < TP; u++) acc[c][u] = 0.f;

  const int in_b = S * t0 - PADL;

  for (int c0 = 0; c0 < CIN; c0 += CC) {
    __syncthreads();
    for (int i = tid; i < CC * SPAN; i += 256) {
      int ci = i / SPAN;
      int j  = i - ci * SPAN;
      int tin = in_b + j;
      float v = 0.f;
      if (tin >= 0 && tin < Tin)
        v = in[(size_t)(b * CIN + c0 + ci) * Tin + tin];
      if (RELU_IN) v = fmaxf(v, 0.f);
      xs[ci * XSP + j] = v;
    }
    __syncthreads();

    for (int ci = 0; ci < CC; ci++) {
      float xv[TP][K];
      #pragma unroll
      for (int u = 0; u < TP; u++)
        #pragma unroll
        for (int k = 0; k < K; k++)
          xv[u][k] = xs[ci * XSP + S * (lane + 64 * u) + k];

      // wave-uniform weight row -> scalar loads (SMEM pipe)
      const float* wr = wT + (size_t)((c0 + ci) * (COUT * KP) + wvu * (CO_PER * KP));

      if constexpr (K == 1) {
        #pragma unroll
        for (int cq = 0; cq < CO_PER / 4; cq++) {
          float4 wc = *(const float4*)(wr + cq * 4);   // 4 consecutive co
          #pragma unroll
          for (int u = 0; u < TP; u++) {
            acc[cq*4+0][u] = fmaf(xv[u][0], wc.x, acc[cq*4+0][u]);
            acc[cq*4+1][u] = fmaf(xv[u][0], wc.y, acc[cq*4+1][u]);
            acc[cq*4+2][u] = fmaf(xv[u][0], wc.z, acc[cq*4+2][u]);
            acc[cq*4+3][u] = fmaf(xv[u][0], wc.w, acc[cq*4+3][u]);
          }
        }
      } else {
        #pragma unroll
        for (int cg = 0; cg < CO_PER; cg++) {
          float4 wc = *(const float4*)(wr + cg * 4);
          #pragma unroll
          for (int u = 0; u < TP; u++) {
            float a = acc[cg][u];
            a = fmaf(xv[u][0], wc.x, a);
            a = fmaf(xv[u][1], wc.y, a);
            a = fmaf(xv[u][2], wc.z, a);
            if constexpr (K == 4) a = fmaf(xv[u][3], wc.w, a);
            acc[cg][u] = a;
          }
        }
      }
    }
  }

  if constexpr (!TRANSPOSED) {
    #pragma unroll
    for (int cg = 0; cg < CO_PER; cg++) {
      int co = wvu * CO_PER + cg;                      // uniform
      float bs = 0.f;
      if constexpr (HAS_BIAS) bs = bias[co];
      #pragma unroll
      for (int u = 0; u < TP; u++) {
        int t = t0 + lane + 64 * u;
        float v = acc[cg][u] + bs;
        if (RELU_OUT) v = fmaxf(v, 0.f);
        size_t oi = (size_t)(b * COUT + co) * Tout + t;
        if constexpr (ACCUM) out[oi] += v;
        else out[oi] = v;
      }
    }
  } else {
    __syncthreads();
    #pragma unroll
    for (int cg = 0; cg < CO_PER; cg++) {
      int co = wvu * CO_PER + cg;
      float bs = HAS_BIAS ? bias[co] : 0.f;
      #pragma unroll
      for (int u = 0; u < TP; u++)
        ts[(lane + 64 * u) * 65 + co] = acc[cg][u] + bs;
    }
    __syncthreads();
    const size_t base = ((size_t)b * Tout + t0) * COUT;
    for (int i = tid; i < TT * COUT; i += 256) {
      int tl = i >> 6;
      int co = i & 63;
      out[base + i] = ts[tl * 65 + co];
    }
  }
}

// ---- prep: weight transposes + Wc = wpq@w_out + bc + cnorm ---------------
__global__ __launch_bounds__(256) void prep_k(
    const float* __restrict__ w1, const float* __restrict__ w2,
    const float* __restrict__ w3,
    const float* __restrict__ r0a, const float* __restrict__ r0b,
    const float* __restrict__ r1a, const float* __restrict__ r1b,
    const float* __restrict__ wout, const float* __restrict__ bout,
    const float* __restrict__ wpq, const float* __restrict__ bpq,
    const float* __restrict__ cb,
    float* __restrict__ w1T, float* __restrict__ w2T, float* __restrict__ w3T,
    float* __restrict__ r0aT, float* __restrict__ r0bT,
    float* __restrict__ r1aT, float* __restrict__ r1bT,
    float* __restrict__ WcT, float* __restrict__ bc, float* __restrict__ cnorm)
{
  const int gt = blockIdx.x * 256 + threadIdx.x;
  const int NT = gridDim.x * 256;
  // K=4 convs: (co,ci,4) -> [ci][co*4+k]
  for (int i = gt; i < 64 * 64 * 4; i += NT) {
    int co = i >> 8, r = i & 255, ci = r >> 2, k = r & 3;
    w1T[ci * 256 + co * 4 + k] = w1[i];
  }
  for (int i = gt; i < 128 * 64 * 4; i += NT) {
    int co = i >> 8, r = i & 255, ci = r >> 2, k = r & 3;
    w2T[ci * 512 + co * 4 + k] = w2[i];
  }
  // K=3 convs: (co,ci,3) -> [ci][co*4+k] (slot k=3 unused)
  for (int i = gt; i < 128 * 128 * 3; i += NT) {
    int co = i / 384, r = i - co * 384, ci = r / 3, k = r - ci * 3;
    w3T[ci * 512 + co * 4 + k] = w3[i];
  }
  for (int i = gt; i < 64 * 128 * 3; i += NT) {
    int co = i / 384, r = i - co * 384, ci = r / 3, k = r - ci * 3;
    r0aT[ci * 256 + co * 4 + k] = r0a[i];
    r1aT[ci * 256 + co * 4 + k] = r1a[i];
  }
  // K=1 convs: (co,ci) -> [ci][co]
  for (int i = gt; i < 128 * 64; i += NT) {
    int co = i >> 6, ci = i & 63;
    r0bT[ci * 128 + co] = r0b[i];
    r1bT[ci * 128 + co] = r1b[i];
  }
  // WcT[ci][d] = sum_e wpq[d][e] * w_out[e][ci]
  for (int i = gt; i < 128 * 64; i += NT) {
    int ci = i >> 6, d = i & 63;
    float s = 0.f;
    for (int e = 0; e < 64; e++) s = fmaf(wpq[d * 64 + e], wout[e * 128 + ci], s);
    WcT[ci * 64 + d] = s;
  }
  for (int i = gt; i < 64; i += NT) {
    float s = bpq[i];
    for (int e = 0; e < 64; e++) s = fmaf(wpq[i * 64 + e], bout[e], s);
    bc[i] = s;
  }
  for (int k = gt; k < 512; k += NT) {
    float s = 0.f;
    for (int d = 0; d < 64; d++) { float c = cb[k * 64 + d]; s = fmaf(c, c, s); }
    cnorm[k] = s;
  }
}

// ---- VQ: 128 points/block (2/lane), codebook rows via scalar loads -------
__global__ __launch_bounds__(256) void vq_k(
    const float* __restrict__ ze,        // (N,64), 8B-aligned base
    const float* __restrict__ cb,        // (512,64)
    const float* __restrict__ cnorm,     // (512)
    float* __restrict__ zq_out,          // (N,64), 4B-aligned base
    float* __restrict__ enc,             // (N,512), 8B-aligned base
    float* __restrict__ idx_out,         // (N)
    int* __restrict__ counts, float* __restrict__ loss_accum)
{
  __shared__ float rv0[256], rv1[256];
  __shared__ int   ri0[256], ri1[256];
  __shared__ int   idx_s[128];
  __shared__ float ls[4];

  const int tid  = threadIdx.x;
  const int lane = tid & 63;
  const int wv   = tid >> 6;
  const int wvu  = __builtin_amdgcn_readfirstlane(wv);
  const int n0   = blockIdx.x * 128;

  float zr0[64], zr1[64];
  {
    const float* zp0 = ze + (size_t)(n0 + lane) * 64;
    const float* zp1 = ze + (size_t)(n0 + 64 + lane) * 64;
    #pragma unroll
    for (int j = 0; j < 32; j++) {
      float2 a = *(const float2*)(zp0 + 2 * j);
      float2 b = *(const float2*)(zp1 + 2 * j);
      zr0[2 * j] = a.x; zr0[2 * j + 1] = a.y;
      zr1[2 * j] = b.x; zr1[2 * j + 1] = b.y;
    }
  }

  float best0 = 3.4e38f, best1 = 3.4e38f;
  int   bi0 = 0, bi1 = 0;

  #pragma unroll 2
  for (int r = 0; r < 128; r++) {
    const int c = wvu * 128 + r;                       // uniform
    const float* crow = cb + (size_t)c * 64;           // -> s_load
    float s00 = 0.f, s01 = 0.f, s02 = 0.f, s03 = 0.f;
    float s10 = 0.f, s11 = 0.f, s12 = 0.f, s13 = 0.f;
    #pragma unroll
    for (int d = 0; d < 64; d += 4) {
      float4 cv = *(const float4*)(crow + d);
      s00 = fmaf(cv.x, zr0[d],     s00);
      s01 = fmaf(cv.y, zr0[d + 1], s01);
      s02 = fmaf(cv.z, zr0[d + 2], s02);
      s03 = fmaf(cv.w, zr0[d + 3], s03);
      s10 = fmaf(cv.x, zr1[d],     s10);
      s11 = fmaf(cv.y, zr1[d + 1], s11);
      s12 = fmaf(cv.z, zr1[d + 2], s12);
      s13 = fmaf(cv.w, zr1[d + 3], s13);
    }
    float cn = cnorm[c];
    float d0 = cn - 2.f * ((s00 + s01) + (s02 + s03));
    float d1 = cn - 2.f * ((s10 + s11) + (s12 + s13));
    if (d0 < best0) { best0 = d0; bi0 = c; }
    if (d1 < best1) { best1 = d1; bi1 = c; }
  }

  rv0[wv * 64 + lane] = best0; ri0[wv * 64 + lane] = bi0;
  rv1[wv * 64 + lane] = best1; ri1[wv * 64 + lane] = bi1;
  __syncthreads();
  if (wv == 0) {
    float bv = rv0[lane]; int bi = ri0[lane];
    #pragma unroll
    for (int w = 1; w < 4; w++) {
      float v = rv0[w * 64 + lane]; int i2 = ri0[w * 64 + lane];
      if (v < bv || (v == bv && i2 < bi)) { bv = v; bi = i2; }
    }
    idx_s[lane] = bi;
    idx_out[n0 + lane] = (float)bi;
    atomicAdd(&counts[bi], 1);
  } else if (wv == 1) {
    float bv = rv1[lane]; int bi = ri1[lane];
    #pragma unroll
    for (int w = 1; w < 4; w++) {
      float v = rv1[w * 64 + lane]; int i2 = ri1[w * 64 + lane];
      if (v < bv || (v == bv && i2 < bi)) { bv = v; bi = i2; }
    }
    idx_s[64 + lane] = bi;
    idx_out[n0 + 64 + lane] = (float)bi;
    atomicAdd(&counts[bi], 1);
  }
  __syncthreads();

  // z_q gather + loss (linear, coalesced; cb row reads wave-uniform)
  float lsum = 0.f;
  const size_t obase = (size_t)n0 * 64;
  #pragma unroll
  for (int j = 0; j < 32; j++) {
    int pos = j * 256 + tid;
    int p = pos >> 6, d = pos & 63;
    int id  = idx_s[p];
    float zq  = cb[id * 64 + d];
    float zev = ze[obase + pos];
    float df  = zq - zev;
    lsum = fmaf(df, df, lsum);
    zq_out[obase + pos] = zq;
  }
  #pragma unroll
  for (int off = 32; off; off >>= 1) lsum += __shfl_down(lsum, off, 64);
  if (lane == 0) ls[wv] = lsum;

  // encodings one-hot rows (fused; replaces 134 MB memset), float2 stores
  for (int p = 0; p < 128; p++) {
    int id = idx_s[p];
    float2 v;
    v.x = (2 * tid     == id) ? 1.0f : 0.0f;
    v.y = (2 * tid + 1 == id) ? 1.0f : 0.0f;
    *(float2*)(enc + (size_t)(n0 + p) * 512 + 2 * tid) = v;
  }

  __syncthreads();
  if (tid == 0) atomicAdd(loss_accum, ls[0] + ls[1] + ls[2] + ls[3]);
}

// ---- finalize ------------------------------------------------------------
__global__ __launch_bounds__(256) void fin_k(
    const int* __restrict__ counts, const float* __restrict__ loss_accum,
    float* __restrict__ loss_out, float* __restrict__ perp_out)
{
  __shared__ float sd[256];
  const int tid = threadIdx.x;
  float h = 0.f;
  for (int k = tid; k < 512; k += 256) {
    float em = (float)counts[k] * (1.0f / 65536.0f);
    h += em * logf(em + 1e-10f);
  }
  sd[tid] = h;
  __syncthreads();
  for (int s = 128; s; s >>= 1) {
    if (tid < s) sd[tid] += sd[tid + s];
    __syncthreads();
  }
  if (tid == 0) {
    *perp_out = expf(-sd[0]);
    *loss_out = *loss_accum * 1.25f / 4194304.f;
  }
}

extern "C" void kernel_launch(void* const* d_in, const int* in_sizes, int n_in,
                              void* d_out, int out_size, void* d_ws, size_t ws_size,
                              hipStream_t stream)
{
  const float* x    = (const float*)d_in[0];
  const float* w1   = (const float*)d_in[1];
  const float* b1   = (const float*)d_in[2];
  const float* w2   = (const float*)d_in[3];
  const float* b2   = (const float*)d_in[4];
  const float* w3   = (const float*)d_in[5];
  const float* b3   = (const float*)d_in[6];
  const float* r0a  = (const float*)d_in[7];
  const float* r0b  = (const float*)d_in[8];
  const float* r1a  = (const float*)d_in[9];
  const float* r1b  = (const float*)d_in[10];
  const float* wout = (const float*)d_in[11];
  const float* bout = (const float*)d_in[12];
  const float* wpq  = (const float*)d_in[13];
  const float* bpq  = (const float*)d_in[14];
  const float* cb   = (const float*)d_in[15];

  float* out = (float*)d_out;
  float* f   = (float*)d_ws;

  float* buf0 = f;                      // 8.4M floats
  float* buf1 = f + 8388608;            // 8.4M floats
  float* WB   = f + 16777216;           // weight region
  float* w1T  = WB;                     // 16384
  float* w2T  = WB + 16384;             // 32768
  float* w3T  = WB + 49152;             // 65536
  float* r0aT = WB + 114688;            // 32768
  float* r0bT = WB + 147456;            // 8192
  float* r1aT = WB + 155648;            // 32768
  float* r1bT = WB + 188416;            // 8192
  float* WcT  = WB + 196608;            // 8192
  float* bc   = WB + 204800;            // 64
  float* cnorm= WB + 204864;            // 512
  int*   counts = (int*)(WB + 205376);  // 512
  float* lossa  = WB + 205888;          // 1

  // output layout (floats): loss | z_q_st | perp | z_e | encodings | indices
  float* loss_out = out;
  float* zq_out   = out + 1;
  float* perp_out = out + 4194305;
  float* ze_out   = out + 4194306;
  float* enc_out  = out + 8388610;
  float* idx_out  = out + 41943042;

  prep_k<<<dim3(16), dim3(256), 0, stream>>>(
      w1, w2, w3, r0a, r0b, r1a, r1b, wout, bout, wpq, bpq, cb,
      w1T, w2T, w3T, r0aT, r0bT, r1aT, r1bT, WcT, bc, cnorm);
  hipMemsetAsync(counts, 0, 2052, stream);

  conv_k<64,64,4,2,2,  false,true, true, false,false>
      <<<dim3(16,64), dim3(256), 0, stream>>>(x,    w1T, b1, buf0, 4096, 2048);
  conv_k<64,128,4,2,2, false,true, true, false,false>
      <<<dim3(8,64), dim3(256), 0, stream>>>(buf0, w2T, b2, buf1, 2048, 1024);
  conv_k<128,128,3,1,2,false,false,true, false,false>
      <<<dim3(8,64), dim3(256), 0, stream>>>(buf1, w3T, b3, buf0, 1024, 1024);
  conv_k<128,64,3,1,2, true, true, false,false,false>
      <<<dim3(8,64), dim3(256), 0, stream>>>(buf0, r0aT, nullptr, buf1, 1024, 1024);
  conv_k<64,128,1,1,2, false,false,false,true, false>
      <<<dim3(8,64), dim3(256), 0, stream>>>(buf1, r0bT, nullptr, buf0, 1024, 1024);
  conv_k<128,64,3,1,2, true, true, false,false,false>
      <<<dim3(8,64), dim3(256), 0, stream>>>(buf0, r1aT, nullptr, buf1, 1024, 1024);
  conv_k<64,128,1,1,2, false,false,false,true, false>
      <<<dim3(8,64), dim3(256), 0, stream>>>(buf1, r1bT, nullptr, buf0, 1024, 1024);
  conv_k<128,64,1,1,2, true, false,true, false,true >
      <<<dim3(8,64), dim3(256), 0, stream>>>(buf0, WcT, bc, ze_out, 1024, 1024);

  vq_k<<<dim3(512), dim3(256), 0, stream>>>(ze_out, cb, cnorm, zq_out, enc_out,
                                            idx_out, counts, lossa);
  fin_k<<<dim3(1), dim3(256), 0, stream>>>(counts, lossa, loss_out, perp_out);
}

// Round 3
// 1048.545 us; speedup vs baseline: 1.2569x; 1.0026x over previous
//
#include <hip/hip_runtime.h>
#include <math.h>

// ---------------------------------------------------------------------------
// VQ-VAE encoder, fp32. B=64, Cin=64, T=4096; h=128, rh=64, D=64, K=512.
// Round 3: weights/codebook loaded via explicit s_load_dwordx16 into SGPR
// tuples (scalar pipe; r2's readfirstlane pointers still emitted vector
// loads -> latency-bound, VALUBusy 17%). Lanes own contiguous t-pairs so
// x-tile LDS reads are b128/b64 and global stores dwordx2. co-split grids
// for 4 blocks/CU. encodings one-hot written as float4.
// ---------------------------------------------------------------------------

typedef __attribute__((ext_vector_type(16))) float sf16;

template<int N>
__device__ __forceinline__ void sload(const float* p, sf16 (&W)[N]) {
  if constexpr (N == 1) {
    asm volatile("s_load_dwordx16 %0, %1, 0\n\t"
                 "s_waitcnt lgkmcnt(0)"
                 : "=s"(W[0]) : "s"(p));
  } else if constexpr (N == 2) {
    asm volatile("s_load_dwordx16 %0, %2, 0\n\t"
                 "s_load_dwordx16 %1, %2, 64\n\t"
                 "s_waitcnt lgkmcnt(0)"
                 : "=s"(W[0]), "=s"(W[1]) : "s"(p));
  } else {
    static_assert(N == 4, "unsupported");
    asm volatile("s_load_dwordx16 %0, %4, 0\n\t"
                 "s_load_dwordx16 %1, %4, 64\n\t"
                 "s_load_dwordx16 %2, %4, 128\n\t"
                 "s_load_dwordx16 %3, %4, 192\n\t"
                 "s_waitcnt lgkmcnt(0)"
                 : "=s"(W[0]), "=s"(W[1]), "=s"(W[2]), "=s"(W[3]) : "s"(p));
  }
}

template<int CIN, int COUT, int K, int S, int CO_PER,
         bool RELU_IN, bool RELU_OUT, bool HAS_BIAS, bool ACCUM, bool TRANSPOSED>
__global__ __launch_bounds__(256) void conv_k(
    const float* __restrict__ in, const float* __restrict__ wT,
    const float* __restrict__ bias, float* __restrict__ out,
    int Tin, int Tout)
{
  constexpr int CC   = 32;                   // ci chunk staged in LDS
  constexpr int TT   = 128;                  // t-tile; lane owns t-pair
  constexpr int PADL = (K == 1) ? 0 : 1;
  constexpr int SPAN = S * (TT - 1) + K;
  constexpr int XSP  = (S == 2) ? 260 : 132; // 16B-aligned row stride
  constexpr int KP   = (K == 1) ? 1 : 4;
  constexpr int NW   = (CO_PER * KP + 15) / 16;  // sf16 chunks per ci

  static_assert(CO_PER * KP % 16 == 0 || KP == 1, "layout");
  static_assert(!TRANSPOSED || COUT == 64, "transpose path assumes COUT==64");

  __shared__ __align__(16) float xs[CC * XSP];
  __shared__ float ts[TRANSPOSED ? (TT * 65) : 1];

  const int b    = blockIdx.y;
  const int t0   = blockIdx.x * TT;
  const int tid  = threadIdx.x;
  const int lane = tid & 63;
  const int wvu  = __builtin_amdgcn_readfirstlane(tid >> 6);
  const int co0  = blockIdx.z * (4 * CO_PER) + wvu * CO_PER;

  float acc[CO_PER][2];
  #pragma unroll
  for (int c = 0; c < CO_PER; c++) { acc[c][0] = 0.f; acc[c][1] = 0.f; }

  const int in_b = S * t0 - PADL;
  const float* wp = wT + (size_t)co0 * KP;   // wave's co slice base

  for (int c0 = 0; c0 < CIN; c0 += CC) {
    __syncthreads();
    for (int i = tid; i < CC * SPAN; i += 256) {
      int ci = i / SPAN;
      int j  = i - ci * SPAN;
      int tin = in_b + j;
      float v = 0.f;
      if (tin >= 0 && tin < Tin)
        v = in[(size_t)(b * CIN + c0 + ci) * Tin + tin];
      if (RELU_IN) v = fmaxf(v, 0.f);
      xs[ci * XSP + j] = v;
    }
    __syncthreads();

    for (int ci = 0; ci < CC; ci++) {
      sf16 W[NW];
      sload<NW>(wp + (size_t)(c0 + ci) * (COUT * KP), W);

      float xv[2][K];
      const float* xr = &xs[ci * XSP + S * 2 * lane];
      if constexpr (S == 2) {                 // K==4, offsets 2u+k in [0..5]
        float4 a = *(const float4*)xr;        // 16B aligned
        float2 c = *(const float2*)(xr + 4);
        xv[0][0]=a.x; xv[0][1]=a.y; xv[0][2]=a.z; xv[0][3]=a.w;
        xv[1][0]=a.z; xv[1][1]=a.w; xv[1][2]=c.x; xv[1][3]=c.y;
      } else if constexpr (K == 3) {          // offsets u+k in [0..3]
        float2 a = *(const float2*)xr;
        float2 c = *(const float2*)(xr + 2);
        xv[0][0]=a.x; xv[0][1]=a.y; xv[0][2]=c.x;
        xv[1][0]=a.y; xv[1][1]=c.x; xv[1][2]=c.y;
      } else {                                // K==1
        float2 a = *(const float2*)xr;
        xv[0][0]=a.x; xv[1][0]=a.y;
      }

      #pragma unroll
      for (int cg = 0; cg < CO_PER; cg++) {
        #pragma unroll
        for (int u = 0; u < 2; u++) {
          float a = acc[cg][u];
          #pragma unroll
          for (int k = 0; k < K; k++) {
            constexpr int dummy = 0; (void)dummy;
            a = fmaf(xv[u][k], W[(cg * KP + k) >> 4][(cg * KP + k) & 15], a);
          }
          acc[cg][u] = a;
        }
      }
    }
  }

  if constexpr (!TRANSPOSED) {
    const int t = t0 + 2 * lane;
    #pragma unroll
    for (int cg = 0; cg < CO_PER; cg++) {
      int co = co0 + cg;
      float bs = 0.f;
      if constexpr (HAS_BIAS) bs = bias[co];
      float2 v;
      v.x = acc[cg][0] + bs;
      v.y = acc[cg][1] + bs;
      if (RELU_OUT) { v.x = fmaxf(v.x, 0.f); v.y = fmaxf(v.y, 0.f); }
      float2* op = (float2*)(out + (size_t)(b * COUT + co) * Tout + t);
      if constexpr (ACCUM) {
        float2 o = *op;
        v.x += o.x; v.y += o.y;
      }
      *op = v;
    }
  } else {
    __syncthreads();
    #pragma unroll
    for (int cg = 0; cg < CO_PER; cg++) {
      int co = co0 + cg;
      float bs = HAS_BIAS ? bias[co] : 0.f;
      ts[(2 * lane)     * 65 + co] = acc[cg][0] + bs;
      ts[(2 * lane + 1) * 65 + co] = acc[cg][1] + bs;
    }
    __syncthreads();
    const size_t base = ((size_t)b * Tout + t0) * COUT;
    for (int i = tid; i < TT * 64; i += 256) {
      int tl = i >> 6;
      int co = i & 63;
      out[base + i] = ts[tl * 65 + co];
    }
  }
}

// ---- prep: weight transposes + Wc = wpq@w_out + bc + cnorm ---------------
__global__ __launch_bounds__(256) void prep_k(
    const float* __restrict__ w1, const float* __restrict__ w2,
    const float* __restrict__ w3,
    const float* __restrict__ r0a, const float* __restrict__ r0b,
    const float* __restrict__ r1a, const float* __restrict__ r1b,
    const float* __restrict__ wout, const float* __restrict__ bout,
    const float* __restrict__ wpq, const float* __restrict__ bpq,
    const float* __restrict__ cb,
    float* __restrict__ w1T, float* __restrict__ w2T, float* __restrict__ w3T,
    float* __restrict__ r0aT, float* __restrict__ r0bT,
    float* __restrict__ r1aT, float* __restrict__ r1bT,
    float* __restrict__ WcT, float* __restrict__ bc, float* __restrict__ cnorm)
{
  const int gt = blockIdx.x * 256 + threadIdx.x;
  const int NT = gridDim.x * 256;
  for (int i = gt; i < 64 * 64 * 4; i += NT) {
    int co = i >> 8, r = i & 255, ci = r >> 2, k = r & 3;
    w1T[ci * 256 + co * 4 + k] = w1[i];
  }
  for (int i = gt; i < 128 * 64 * 4; i += NT) {
    int co = i >> 8, r = i & 255, ci = r >> 2, k = r & 3;
    w2T[ci * 512 + co * 4 + k] = w2[i];
  }
  for (int i = gt; i < 128 * 128 * 4; i += NT) {           // zero pad slots
    int ci = (i >> 9), co = (i >> 2) & 127, k = i & 3;
    w3T[ci * 512 + co * 4 + k] = (k < 3) ? w3[co * 384 + ci * 3 + k] : 0.f;
  }
  for (int i = gt; i < 64 * 128 * 4; i += NT) {
    int ci = (i >> 8), co = (i >> 2) & 63, k = i & 3;
    float a = (k < 3) ? r0a[co * 384 + ci * 3 + k] : 0.f;
    float b = (k < 3) ? r1a[co * 384 + ci * 3 + k] : 0.f;
    r0aT[ci * 256 + co * 4 + k] = a;
    r1aT[ci * 256 + co * 4 + k] = b;
  }
  for (int i = gt; i < 128 * 64; i += NT) {
    int co = i >> 6, ci = i & 63;
    r0bT[ci * 128 + co] = r0b[i];
    r1bT[ci * 128 + co] = r1b[i];
  }
  for (int i = gt; i < 128 * 64; i += NT) {
    int ci = i >> 6, d = i & 63;
    float s = 0.f;
    for (int e = 0; e < 64; e++) s = fmaf(wpq[d * 64 + e], wout[e * 128 + ci], s);
    WcT[ci * 64 + d] = s;
  }
  for (int i = gt; i < 64; i += NT) {
    float s = bpq[i];
    for (int e = 0; e < 64; e++) s = fmaf(wpq[i * 64 + e], bout[e], s);
    bc[i] = s;
  }
  for (int k = gt; k < 512; k += NT) {
    float s = 0.f;
    for (int d = 0; d < 64; d++) { float c = cb[k * 64 + d]; s = fmaf(c, c, s); }
    cnorm[k] = s;
  }
}

// ---- VQ: 128 points/block (2/lane), codebook rows via s_load -------------
__global__ __launch_bounds__(256) void vq_k(
    const float* __restrict__ ze,        // (N,64)
    const float* __restrict__ cb,        // (512,64)
    const float* __restrict__ cnorm,     // (512)
    float* __restrict__ zq_out,          // (N,64)
    float* __restrict__ enc,             // (N,512)
    float* __restrict__ idx_out,         // (N)
    int* __restrict__ counts, float* __restrict__ loss_accum)
{
  __shared__ float rv0[256], rv1[256];
  __shared__ int   ri0[256], ri1[256];
  __shared__ int   idx_s[128];
  __shared__ float ls[4];

  const int tid  = threadIdx.x;
  const int lane = tid & 63;
  const int wv   = tid >> 6;
  const int wvu  = __builtin_amdgcn_readfirstlane(wv);
  const int n0   = blockIdx.x * 128;

  float zr0[64], zr1[64];
  {
    const float* zp0 = ze + (size_t)(n0 + lane) * 64;
    const float* zp1 = ze + (size_t)(n0 + 64 + lane) * 64;
    #pragma unroll
    for (int j = 0; j < 32; j++) {
      float2 a = *(const float2*)(zp0 + 2 * j);
      float2 b = *(const float2*)(zp1 + 2 * j);
      zr0[2 * j] = a.x; zr0[2 * j + 1] = a.y;
      zr1[2 * j] = b.x; zr1[2 * j + 1] = b.y;
    }
  }

  float best0 = 3.4e38f, best1 = 3.4e38f;
  int   bi0 = 0, bi1 = 0;

  #pragma unroll 1
  for (int r = 0; r < 128; r++) {
    const int c = wvu * 128 + r;
    sf16 W[4];
    sload<4>(cb + (size_t)c * 64, W);
    float s00 = 0.f, s01 = 0.f, s02 = 0.f, s03 = 0.f;
    float s10 = 0.f, s11 = 0.f, s12 = 0.f, s13 = 0.f;
    #pragma unroll
    for (int d = 0; d < 64; d += 4) {
      float c0 = W[d >> 4][(d & 15) + 0];
      float c1 = W[d >> 4][(d & 15) + 1];
      float c2 = W[d >> 4][(d & 15) + 2];
      float c3 = W[d >> 4][(d & 15) + 3];
      s00 = fmaf(c0, zr0[d],     s00);
      s01 = fmaf(c1, zr0[d + 1], s01);
      s02 = fmaf(c2, zr0[d + 2], s02);
      s03 = fmaf(c3, zr0[d + 3], s03);
      s10 = fmaf(c0, zr1[d],     s10);
      s11 = fmaf(c1, zr1[d + 1], s11);
      s12 = fmaf(c2, zr1[d + 2], s12);
      s13 = fmaf(c3, zr1[d + 3], s13);
    }
    float cn = cnorm[c];
    float d0 = cn - 2.f * ((s00 + s01) + (s02 + s03));
    float d1 = cn - 2.f * ((s10 + s11) + (s12 + s13));
    if (d0 < best0) { best0 = d0; bi0 = c; }
    if (d1 < best1) { best1 = d1; bi1 = c; }
  }

  rv0[wv * 64 + lane] = best0; ri0[wv * 64 + lane] = bi0;
  rv1[wv * 64 + lane] = best1; ri1[wv * 64 + lane] = bi1;
  __syncthreads();
  if (wv == 0) {
    float bv = rv0[lane]; int bi = ri0[lane];
    #pragma unroll
    for (int w = 1; w < 4; w++) {
      float v = rv0[w * 64 + lane]; int i2 = ri0[w * 64 + lane];
      if (v < bv || (v == bv && i2 < bi)) { bv = v; bi = i2; }
    }
    idx_s[lane] = bi;
    idx_out[n0 + lane] = (float)bi;
    atomicAdd(&counts[bi], 1);
  } else if (wv == 1) {
    float bv = rv1[lane]; int bi = ri1[lane];
    #pragma unroll
    for (int w = 1; w < 4; w++) {
      float v = rv1[w * 64 + lane]; int i2 = ri1[w * 64 + lane];
      if (v < bv || (v == bv && i2 < bi)) { bv = v; bi = i2; }
    }
    idx_s[64 + lane] = bi;
    idx_out[n0 + 64 + lane] = (float)bi;
    atomicAdd(&counts[bi], 1);
  }
  __syncthreads();

  // z_q gather + loss, linear coalesced
  float lsum = 0.f;
  const size_t obase = (size_t)n0 * 64;
  #pragma unroll
  for (int j = 0; j < 32; j++) {
    int pos = j * 256 + tid;
    int p = pos >> 6, d = pos & 63;
    int id  = idx_s[p];
    float zq  = cb[id * 64 + d];
    float zev = ze[obase + pos];
    float df  = zq - zev;
    lsum = fmaf(df, df, lsum);
    zq_out[obase + pos] = zq;
  }
  #pragma unroll
  for (int off = 32; off; off >>= 1) lsum += __shfl_down(lsum, off, 64);
  if (lane == 0) ls[wv] = lsum;

  // encodings one-hot: float4 stores, 2 rows per pass (256 thr x 4 = 1024 f)
  for (int pp = 0; pp < 128; pp += 2) {
    int p   = pp + (tid >> 7);
    int col = (tid & 127) * 4;
    int id  = idx_s[p];
    float4 v;
    v.x = (col     == id) ? 1.0f : 0.0f;
    v.y = (col + 1 == id) ? 1.0f : 0.0f;
    v.z = (col + 2 == id) ? 1.0f : 0.0f;
    v.w = (col + 3 == id) ? 1.0f : 0.0f;
    *(float4*)(enc + (size_t)(n0 + p) * 512 + col) = v;
  }

  __syncthreads();
  if (tid == 0) atomicAdd(loss_accum, ls[0] + ls[1] + ls[2] + ls[3]);
}

// ---- finalize ------------------------------------------------------------
__global__ __launch_bounds__(256) void fin_k(
    const int* __restrict__ counts, const float* __restrict__ loss_accum,
    float* __restrict__ loss_out, float* __restrict__ perp_out)
{
  __shared__ float sd[256];
  const int tid = threadIdx.x;
  float h = 0.f;
  for (int k = tid; k < 512; k += 256) {
    float em = (float)counts[k] * (1.0f / 65536.0f);
    h += em * logf(em + 1e-10f);
  }
  sd[tid] = h;
  __syncthreads();
  for (int s = 128; s; s >>= 1) {
    if (tid < s) sd[tid] += sd[tid + s];
    __syncthreads();
  }
  if (tid == 0) {
    *perp_out = expf(-sd[0]);
    *loss_out = *loss_accum * 1.25f / 4194304.f;
  }
}

extern "C" void kernel_launch(void* const* d_in, const int* in_sizes, int n_in,
                              void* d_out, int out_size, void* d_ws, size_t ws_size,
                              hipStream_t stream)
{
  const float* x    = (const float*)d_in[0];
  const float* w1   = (const float*)d_in[1];
  const float* b1   = (const float*)d_in[2];
  const float* w2   = (const float*)d_in[3];
  const float* b2   = (const float*)d_in[4];
  const float* w3   = (const float*)d_in[5];
  const float* b3   = (const float*)d_in[6];
  const float* r0a  = (const float*)d_in[7];
  const float* r0b  = (const float*)d_in[8];
  const float* r1a  = (const float*)d_in[9];
  const float* r1b  = (const float*)d_in[10];
  const float* wout = (const float*)d_in[11];
  const float* bout = (const float*)d_in[12];
  const float* wpq  = (const float*)d_in[13];
  const float* bpq  = (const float*)d_in[14];
  const float* cb   = (const float*)d_in[15];

  float* out = (float*)d_out;
  float* f   = (float*)d_ws;

  float* buf0 = f;                      // 8.4M floats
  float* buf1 = f + 8388608;            // 8.4M floats
  float* WB   = f + 16777216;
  float* w1T  = WB;                     // 16384
  float* w2T  = WB + 16384;             // 32768
  float* w3T  = WB + 49152;             // 65536 (padded K=4)
  float* r0aT = WB + 114688;            // 32768 (padded)
  float* r0bT = WB + 147456;            // 8192
  float* r1aT = WB + 155648;            // 32768
  float* r1bT = WB + 188416;            // 8192
  float* WcT  = WB + 196608;            // 8192
  float* bc   = WB + 204800;            // 64
  float* cnorm= WB + 204864;            // 512
  int*   counts = (int*)(WB + 205376);  // 512
  float* lossa  = WB + 205888;          // 1

  // output layout (floats): loss | z_q_st | perp | z_e | encodings | indices
  float* loss_out = out;
  float* zq_out   = out + 1;
  float* perp_out = out + 4194305;
  float* ze_out   = out + 4194306;
  float* enc_out  = out + 8388610;
  float* idx_out  = out + 41943042;

  prep_k<<<dim3(16), dim3(256), 0, stream>>>(
      w1, w2, w3, r0a, r0b, r1a, r1b, wout, bout, wpq, bpq, cb,
      w1T, w2T, w3T, r0aT, r0bT, r1aT, r1bT, WcT, bc, cnorm);
  hipMemsetAsync(counts, 0, 2052, stream);

  conv_k<64,64,4,2,16,   false,true, true, false,false>
      <<<dim3(16,64,1), dim3(256), 0, stream>>>(x,    w1T, b1, buf0, 4096, 2048);
  conv_k<64,128,4,2,16,  false,true, true, false,false>
      <<<dim3(8,64,2), dim3(256), 0, stream>>>(buf0, w2T, b2, buf1, 2048, 1024);
  conv_k<128,128,3,1,16, false,false,true, false,false>
      <<<dim3(8,64,2), dim3(256), 0, stream>>>(buf1, w3T, b3, buf0, 1024, 1024);
  conv_k<128,64,3,1,16,  true, true, false,false,false>
      <<<dim3(8,64,1), dim3(256), 0, stream>>>(buf0, r0aT, nullptr, buf1, 1024, 1024);
  conv_k<64,128,1,1,16,  false,false,false,true, false>
      <<<dim3(8,64,2), dim3(256), 0, stream>>>(buf1, r0bT, nullptr, buf0, 1024, 1024);
  conv_k<128,64,3,1,16,  true, true, false,false,false>
      <<<dim3(8,64,1), dim3(256), 0, stream>>>(buf0, r1aT, nullptr, buf1, 1024, 1024);
  conv_k<64,128,1,1,16,  false,false,false,true, false>
      <<<dim3(8,64,2), dim3(256), 0, stream>>>(buf1, r1bT, nullptr, buf0, 1024, 1024);
  conv_k<128,64,1,1,16,  true, false,true, false,true >
      <<<dim3(8,64,1), dim3(256), 0, stream>>>(buf0, WcT, bc, ze_out, 1024, 1024);

  vq_k<<<dim3(512), dim3(256), 0, stream>>>(ze_out, cb, cnorm, zq_out, enc_out,
                                            idx_out, counts, lossa);
  fin_k<<<dim3(1), dim3(256), 0, stream>>>(counts, lossa, loss_out, perp_out);
}

// Round 5
// 739.277 us; speedup vs baseline: 1.7827x; 1.4183x over previous
//
#include <hip/hip_runtime.h>
#include <math.h>

// ---------------------------------------------------------------------------
// VQ-VAE encoder. Round 5: convs on matrix cores via 3-term split-bf16
// (x = h+m+l, w = h+m+l; products hh,hm,mh,mm,hl,lh -> rel err ~2^-27,
// below fp32 eps => argmin-safe). A-fragments loaded per-wave straight from
// global (no LDS staging); x tile staged as 3 bf16 copies in LDS.
// VQ = round-2 kernel (best measured 240us).
// ---------------------------------------------------------------------------

typedef short short8 __attribute__((ext_vector_type(8)));
typedef float f32x4 __attribute__((ext_vector_type(4)));

__device__ __forceinline__ unsigned short bf16hi(float f) {
  unsigned u = __builtin_bit_cast(unsigned, f);
  return (unsigned short)((u + 0x7FFFu + ((u >> 16) & 1u)) >> 16);
}
__device__ __forceinline__ float bf16tof(unsigned short h) {
  unsigned u = ((unsigned)h) << 16;
  return __builtin_bit_cast(float, u);
}
__device__ __forceinline__ void split3(float f, unsigned short& h,
                                       unsigned short& m, unsigned short& l) {
  h = bf16hi(f);
  float r = f - bf16tof(h);
  m = bf16hi(r);
  l = bf16hi(r - bf16tof(m));
}

// ---------------------------------------------------------------------------
// conv kernel: block = 64co x 64t, 4 waves in 2x2 (M-half x N-half).
// ci chunks of 32 (= MFMA K). x tile rows = 32 ci, row stride 40 shorts.
// ---------------------------------------------------------------------------
template<int CIN, int TAPS, int S, bool RELU_IN, bool HAS_BIAS, bool RESID,
         bool CHW_IN, bool OUT_NOGUARD>
__global__ __launch_bounds__(256) void conv_mfma(
    const float* __restrict__ in, const short* __restrict__ Ab,
    const float* __restrict__ bias, const float* __restrict__ resid,
    float* __restrict__ out, int Tin, int Tout, int MTG)
{
  constexpr int nCk   = CIN / 32;
  constexpr int RS    = (S == 2) ? 130 : ((TAPS == 3) ? 66 : 64);
  constexpr int ROWBS = 40;                  // shorts per x-row (80 B)

  __shared__ short xhi[RS * ROWBS];
  __shared__ short xmd[RS * ROWBS];
  __shared__ short xlo[RS * ROWBS];

  const int tid  = threadIdx.x;
  const int lane = tid & 63;
  const int wv   = tid >> 6;
  const int ih   = wv & 1;                   // M-half
  const int jh   = wv >> 1;                  // N-half
  const int tl   = lane & 15;                // n (t-local)
  const int q    = lane >> 4;                // quad
  const int b    = blockIdx.y;
  const int t0   = blockIdx.x * 64;
  const int co0  = blockIdx.z * 64;
  const int COUT = MTG * 16;

  const int rbase = (S == 2) ? (2 * t0) : ((TAPS == 3) ? t0 : (t0 + 1));

  f32x4 acc[2][2] = {};

  for (int ch = 0; ch < nCk; ch++) {
    if (ch) __syncthreads();

    // ---- stage x chunk (32 ci) as h/m/l bf16 ----
    if constexpr (!CHW_IN) {
      for (int i = tid; i < RS * 8; i += 256) {
        int rl = i >> 3;
        int c4 = (i & 7) * 4;
        int rg = rbase + rl;
        const float* sp = in + ((size_t)b * (Tin + 2) + rg) * CIN + ch * 32 + c4;
        float4 v = *(const float4*)sp;
        if (RELU_IN) {
          v.x = fmaxf(v.x, 0.f); v.y = fmaxf(v.y, 0.f);
          v.z = fmaxf(v.z, 0.f); v.w = fmaxf(v.w, 0.f);
        }
        float vv[4] = {v.x, v.y, v.z, v.w};
        unsigned short h[4], m[4], l[4];
        #pragma unroll
        for (int e = 0; e < 4; e++) split3(vv[e], h[e], m[e], l[e]);
        int slot = (S == 2) ? ((rl & 1) * 65 + (rl >> 1)) : rl;
        int off = slot * ROWBS + c4;
        uint2 uh, um, ul;
        uh.x = (unsigned)h[0] | ((unsigned)h[1] << 16);
        uh.y = (unsigned)h[2] | ((unsigned)h[3] << 16);
        um.x = (unsigned)m[0] | ((unsigned)m[1] << 16);
        um.y = (unsigned)m[2] | ((unsigned)m[3] << 16);
        ul.x = (unsigned)l[0] | ((unsigned)l[1] << 16);
        ul.y = (unsigned)l[2] | ((unsigned)l[3] << 16);
        *(uint2*)(xhi + off) = uh;
        *(uint2*)(xmd + off) = um;
        *(uint2*)(xlo + off) = ul;
      }
    } else {
      // conv1: raw x [b][64][Tin], S=2. row rl <-> t_in = 2*t0 + rl - 1.
      if (tid < 32) {
        int cig = ch * 32 + tid;
        int tin = 2 * t0 - 1;
        float v = 0.f;
        if (tin >= 0) v = in[((size_t)b * 64 + cig) * Tin + tin];
        unsigned short h, m, l;
        split3(v, h, m, l);
        xhi[tid] = (short)h;                 // slot 0
        xmd[tid] = (short)m;
        xlo[tid] = (short)l;
      }
      int cil = tid >> 3, tq = tid & 7;
      for (int base = tq * 4; base <= 128; base += 32) {
        int tin0 = 2 * t0 + base;
        const float* sp = in + ((size_t)b * 64 + ch * 32 + cil) * Tin + tin0;
        float vv[4];
        if (tin0 + 3 < Tin) {
          float4 t4 = *(const float4*)sp;
          vv[0] = t4.x; vv[1] = t4.y; vv[2] = t4.z; vv[3] = t4.w;
        } else {
          #pragma unroll
          for (int e = 0; e < 4; e++) vv[e] = (tin0 + e < Tin) ? sp[e] : 0.f;
        }
        #pragma unroll
        for (int e = 0; e < 4; e++) {
          int rl = base + e + 1;
          if (rl <= 129) {
            unsigned short h, m, l;
            split3(vv[e], h, m, l);
            int slot = (rl & 1) * 65 + (rl >> 1);
            xhi[slot * ROWBS + cil] = (short)h;
            xmd[slot * ROWBS + cil] = (short)m;
            xlo[slot * ROWBS + cil] = (short)l;
          }
        }
      }
    }
    __syncthreads();

    // ---- compute ----
    #pragma unroll
    for (int tap = 0; tap < TAPS; tap++) {
      short8 ah[2], am[2], al[2];
      #pragma unroll
      for (int mi = 0; mi < 2; mi++) {
        const short* ab = Ab +
            (size_t)(((ch * TAPS + tap) * MTG + (co0 >> 4) + ih * 2 + mi) * 3) * 512
            + lane * 8;
        ah[mi] = *(const short8*)ab;
        am[mi] = *(const short8*)(ab + 512);
        al[mi] = *(const short8*)(ab + 1024);
      }
      #pragma unroll
      for (int nt = 0; nt < 2; nt++) {
        int tpos = jh * 32 + nt * 16 + tl;
        int slot;
        if constexpr (S == 2)         slot = (tap & 1) * 65 + tpos + (tap >> 1);
        else if constexpr (TAPS == 3) slot = tpos + tap;
        else                          slot = tpos;
        const int xo = slot * ROWBS + q * 8;
        short8 bh = *(const short8*)(xhi + xo);
        short8 bm = *(const short8*)(xmd + xo);
        short8 bl = *(const short8*)(xlo + xo);
        #pragma unroll
        for (int mi = 0; mi < 2; mi++) {
          acc[mi][nt] = __builtin_amdgcn_mfma_f32_16x16x32_bf16(ah[mi], bh, acc[mi][nt], 0, 0, 0);
          acc[mi][nt] = __builtin_amdgcn_mfma_f32_16x16x32_bf16(ah[mi], bm, acc[mi][nt], 0, 0, 0);
          acc[mi][nt] = __builtin_amdgcn_mfma_f32_16x16x32_bf16(am[mi], bh, acc[mi][nt], 0, 0, 0);
          acc[mi][nt] = __builtin_amdgcn_mfma_f32_16x16x32_bf16(am[mi], bm, acc[mi][nt], 0, 0, 0);
          acc[mi][nt] = __builtin_amdgcn_mfma_f32_16x16x32_bf16(ah[mi], bl, acc[mi][nt], 0, 0, 0);
          acc[mi][nt] = __builtin_amdgcn_mfma_f32_16x16x32_bf16(al[mi], bh, acc[mi][nt], 0, 0, 0);
        }
      }
    }
  }

  // ---- epilogue: D layout col=lane&15 (t), row=quad*4+reg (co) ----
  #pragma unroll
  for (int mi = 0; mi < 2; mi++) {
    #pragma unroll
    for (int nt = 0; nt < 2; nt++) {
      int t  = t0 + jh * 32 + nt * 16 + tl;
      int co = co0 + (ih * 2 + mi) * 16 + q * 4;
      f32x4 a = acc[mi][nt];
      float4 v = {a[0], a[1], a[2], a[3]};
      if constexpr (HAS_BIAS) {
        float4 bb = *(const float4*)(bias + co);
        v.x += bb.x; v.y += bb.y; v.z += bb.z; v.w += bb.w;
      }
      if constexpr (RESID) {
        float4 rr = *(const float4*)(resid + ((size_t)b * (Tout + 2) + t + 1) * COUT + co);
        v.x += rr.x; v.y += rr.y; v.z += rr.z; v.w += rr.w;
      }
      float* op;
      if constexpr (OUT_NOGUARD) op = out + ((size_t)b * Tout + t) * COUT + co;
      else                       op = out + ((size_t)b * (Tout + 2) + t + 1) * COUT + co;
      *(float4*)op = v;
    }
  }
}

// ---------------------------------------------------------------------------
// prep: Wc = wpq@w_out (fp32), bc, cnorm
// ---------------------------------------------------------------------------
__global__ __launch_bounds__(256) void prep_small(
    const float* __restrict__ wout, const float* __restrict__ bout,
    const float* __restrict__ wpq, const float* __restrict__ bpq,
    const float* __restrict__ cb,
    float* __restrict__ Wc, float* __restrict__ bc, float* __restrict__ cnorm)
{
  const int tid = threadIdx.x;
  for (int i = tid; i < 64 * 128; i += 256) {
    int d = i >> 7, c = i & 127;
    float s = 0.f;
    for (int e = 0; e < 64; e++) s = fmaf(wpq[d * 64 + e], wout[e * 128 + c], s);
    Wc[i] = s;
  }
  for (int i = tid; i < 64; i += 256) {
    float s = bpq[i];
    for (int e = 0; e < 64; e++) s = fmaf(wpq[i * 64 + e], bout[e], s);
    bc[i] = s;
  }
  for (int k = tid; k < 512; k += 256) {
    float s = 0.f;
    for (int d = 0; d < 64; d++) { float c = cb[k * 64 + d]; s = fmaf(c, c, s); }
    cnorm[k] = s;
  }
}

// ---------------------------------------------------------------------------
// prep: A-fragment buffers, 3-way split, frag-lane order.
// layout: [chunk][tap][mtg][hl=0,1,2][lane][8]; elem co=mtg*16+(lane&15),
//         ci=chunk*32+(lane>>4)*8+j, value w[(co*CIN+ci)*TAPS+tap]
// ---------------------------------------------------------------------------
__device__ __forceinline__ void buildA(const float* w, short* dst,
                                       int COUT, int CIN, int TAPS, int idx)
{
  int lane = idx & 63;
  int rest = idx >> 6;
  int hl   = rest % 3;  rest /= 3;
  int mtg  = rest % (COUT / 16); rest /= (COUT / 16);
  int tap  = rest % TAPS;
  int chunk = rest / TAPS;
  int co  = mtg * 16 + (lane & 15);
  int ci0 = chunk * 32 + (lane >> 4) * 8;
  short v[8];
  #pragma unroll
  for (int j = 0; j < 8; j++) {
    float f = w[((size_t)co * CIN + ci0 + j) * TAPS + tap];
    unsigned short h, m, l;
    h = bf16hi(f);
    float r = f - bf16tof(h);
    m = bf16hi(r);
    l = bf16hi(r - bf16tof(m));
    v[j] = (hl == 0) ? (short)h : ((hl == 1) ? (short)m : (short)l);
  }
  // dst offset: ((((chunk*TAPS+tap)*MTG+mtg)*3+hl)*64+lane)*8
  int MTG = COUT / 16;
  size_t o = ((((size_t)(chunk * TAPS + tap) * MTG + mtg) * 3 + hl) * 64 + lane) * 8;
  #pragma unroll
  for (int j = 0; j < 8; j++) dst[o + j] = v[j];
}

__global__ __launch_bounds__(256) void prep_w_all(
    const float* w1, const float* w2, const float* w3,
    const float* r0a, const float* r0b, const float* r1a, const float* r1b,
    const float* Wc,
    short* A1, short* A2, short* A3, short* A4, short* A5, short* A6,
    short* A7, short* A8)
{
  int g = blockIdx.x * 256 + threadIdx.x;
  // idx counts: 6144,12288,18432,9216,3072,9216,3072,3072 (cum 64512)
  if      (g < 6144)  buildA(w1,  A1, 64,  64,  4, g);
  else if (g < 18432) buildA(w2,  A2, 128, 64,  4, g - 6144);
  else if (g < 36864) buildA(w3,  A3, 128, 128, 3, g - 18432);
  else if (g < 46080) buildA(r0a, A4, 64,  128, 3, g - 36864);
  else if (g < 49152) buildA(r0b, A5, 128, 64,  1, g - 46080);
  else if (g < 58368) buildA(r1a, A6, 64,  128, 3, g - 49152);
  else if (g < 61440) buildA(r1b, A7, 128, 64,  1, g - 58368);
  else if (g < 64512) buildA(Wc,  A8, 64,  128, 1, g - 61440);
}

// ---- zero guard rows of the intermediate slots ---------------------------
__global__ __launch_bounds__(256) void zero_guards(
    float* __restrict__ sA, float* __restrict__ sB1,
    float* __restrict__ sB2, float* __restrict__ sC)
{
  int gt = blockIdx.x * 256 + threadIdx.x;
  int NT = gridDim.x * 256;
  for (int i = gt; i < 64 * 2 * 64; i += NT) {      // slotA: T=2048, C=64
    int b = i >> 7, r = (i >> 6) & 1, c = i & 63;
    sA[((size_t)b * 2050 + r * 2049) * 64 + c] = 0.f;
  }
  for (int i = gt; i < 64 * 2 * 128; i += NT) {     // slotB: T=1024, C=128
    int b = i >> 8, r = (i >> 7) & 1, c = i & 127;
    size_t o = ((size_t)b * 1026 + r * 1025) * 128 + c;
    sB1[o] = 0.f; sB2[o] = 0.f;
  }
  for (int i = gt; i < 64 * 2 * 64; i += NT) {      // slotC: T=1024, C=64
    int b = i >> 7, r = (i >> 6) & 1, c = i & 63;
    sC[((size_t)b * 1026 + r * 1025) * 64 + c] = 0.f;
  }
}

// ---------------------------------------------------------------------------
// VQ (round-2 version) + finalize
// ---------------------------------------------------------------------------
__global__ __launch_bounds__(256) void vq_k(
    const float* __restrict__ ze, const float* __restrict__ cb,
    const float* __restrict__ cnorm,
    float* __restrict__ zq_out, float* __restrict__ enc,
    float* __restrict__ idx_out,
    int* __restrict__ counts, float* __restrict__ loss_accum)
{
  __shared__ float rv0[256], rv1[256];
  __shared__ int   ri0[256], ri1[256];
  __shared__ int   idx_s[128];
  __shared__ float ls[4];

  const int tid  = threadIdx.x;
  const int lane = tid & 63;
  const int wv   = tid >> 6;
  const int wvu  = __builtin_amdgcn_readfirstlane(wv);
  const int n0   = blockIdx.x * 128;

  float zr0[64], zr1[64];
  {
    const float* zp0 = ze + (size_t)(n0 + lane) * 64;
    const float* zp1 = ze + (size_t)(n0 + 64 + lane) * 64;
    #pragma unroll
    for (int j = 0; j < 32; j++) {
      float2 a = *(const float2*)(zp0 + 2 * j);
      float2 b = *(const float2*)(zp1 + 2 * j);
      zr0[2 * j] = a.x; zr0[2 * j + 1] = a.y;
      zr1[2 * j] = b.x; zr1[2 * j + 1] = b.y;
    }
  }

  float best0 = 3.4e38f, best1 = 3.4e38f;
  int   bi0 = 0, bi1 = 0;

  #pragma unroll 2
  for (int r = 0; r < 128; r++) {
    const int c = wvu * 128 + r;
    const float* crow = cb + (size_t)c * 64;
    float s00 = 0.f, s01 = 0.f, s02 = 0.f, s03 = 0.f;
    float s10 = 0.f, s11 = 0.f, s12 = 0.f, s13 = 0.f;
    #pragma unroll
    for (int d = 0; d < 64; d += 4) {
      float4 cv = *(const float4*)(crow + d);
      s00 = fmaf(cv.x, zr0[d],     s00);
      s01 = fmaf(cv.y, zr0[d + 1], s01);
      s02 = fmaf(cv.z, zr0[d + 2], s02);
      s03 = fmaf(cv.w, zr0[d + 3], s03);
      s10 = fmaf(cv.x, zr1[d],     s10);
      s11 = fmaf(cv.y, zr1[d + 1], s11);
      s12 = fmaf(cv.z, zr1[d + 2], s12);
      s13 = fmaf(cv.w, zr1[d + 3], s13);
    }
    float cn = cnorm[c];
    float d0 = cn - 2.f * ((s00 + s01) + (s02 + s03));
    float d1 = cn - 2.f * ((s10 + s11) + (s12 + s13));
    if (d0 < best0) { best0 = d0; bi0 = c; }
    if (d1 < best1) { best1 = d1; bi1 = c; }
  }

  rv0[wv * 64 + lane] = best0; ri0[wv * 64 + lane] = bi0;
  rv1[wv * 64 + lane] = best1; ri1[wv * 64 + lane] = bi1;
  __syncthreads();
  if (wv == 0) {
    float bv = rv0[lane]; int bi = ri0[lane];
    #pragma unroll
    for (int w = 1; w < 4; w++) {
      float v = rv0[w * 64 + lane]; int i2 = ri0[w * 64 + lane];
      if (v < bv || (v == bv && i2 < bi)) { bv = v; bi = i2; }
    }
    idx_s[lane] = bi;
    idx_out[n0 + lane] = (float)bi;
    atomicAdd(&counts[bi], 1);
  } else if (wv == 1) {
    float bv = rv1[lane]; int bi = ri1[lane];
    #pragma unroll
    for (int w = 1; w < 4; w++) {
      float v = rv1[w * 64 + lane]; int i2 = ri1[w * 64 + lane];
      if (v < bv || (v == bv && i2 < bi)) { bv = v; bi = i2; }
    }
    idx_s[64 + lane] = bi;
    idx_out[n0 + 64 + lane] = (float)bi;
    atomicAdd(&counts[bi], 1);
  }
  __syncthreads();

  float lsum = 0.f;
  const size_t obase = (size_t)n0 * 64;
  #pragma unroll
  for (int j = 0; j < 32; j++) {
    int pos = j * 256 + tid;
    int p = pos >> 6, d = pos & 63;
    int id = idx_s[p];
    float zq  = cb[id * 64 + d];
    float zev = ze[obase + pos];
    float df  = zq - zev;
    lsum = fmaf(df, df, lsum);
    zq_out[obase + pos] = zq;
  }
  #pragma unroll
  for (int off = 32; off; off >>= 1) lsum += __shfl_down(lsum, off, 64);
  if (lane == 0) ls[wv] = lsum;

  for (int pp = 0; pp < 128; pp += 2) {
    int p   = pp + (tid >> 7);
    int col = (tid & 127) * 4;
    int id  = idx_s[p];
    float4 v;
    v.x = (col     == id) ? 1.0f : 0.0f;
    v.y = (col + 1 == id) ? 1.0f : 0.0f;
    v.z = (col + 2 == id) ? 1.0f : 0.0f;
    v.w = (col + 3 == id) ? 1.0f : 0.0f;
    *(float4*)(enc + (size_t)(n0 + p) * 512 + col) = v;
  }

  __syncthreads();
  if (tid == 0) atomicAdd(loss_accum, ls[0] + ls[1] + ls[2] + ls[3]);
}

__global__ __launch_bounds__(256) void fin_k(
    const int* __restrict__ counts, const float* __restrict__ loss_accum,
    float* __restrict__ loss_out, float* __restrict__ perp_out)
{
  __shared__ float sd[256];
  const int tid = threadIdx.x;
  float h = 0.f;
  for (int k = tid; k < 512; k += 256) {
    float em = (float)counts[k] * (1.0f / 65536.0f);
    h += em * logf(em + 1e-10f);
  }
  sd[tid] = h;
  __syncthreads();
  for (int s = 128; s; s >>= 1) {
    if (tid < s) sd[tid] += sd[tid + s];
    __syncthreads();
  }
  if (tid == 0) {
    *perp_out = expf(-sd[0]);
    *loss_out = *loss_accum * 1.25f / 4194304.f;
  }
}

// ---------------------------------------------------------------------------
extern "C" void kernel_launch(void* const* d_in, const int* in_sizes, int n_in,
                              void* d_out, int out_size, void* d_ws, size_t ws_size,
                              hipStream_t stream)
{
  const float* x    = (const float*)d_in[0];
  const float* w1   = (const float*)d_in[1];
  const float* b1   = (const float*)d_in[2];
  const float* w2   = (const float*)d_in[3];
  const float* b2   = (const float*)d_in[4];
  const float* w3   = (const float*)d_in[5];
  const float* b3   = (const float*)d_in[6];
  const float* r0a  = (const float*)d_in[7];
  const float* r0b  = (const float*)d_in[8];
  const float* r1a  = (const float*)d_in[9];
  const float* r1b  = (const float*)d_in[10];
  const float* wout = (const float*)d_in[11];
  const float* bout = (const float*)d_in[12];
  const float* wpq  = (const float*)d_in[13];
  const float* bpq  = (const float*)d_in[14];
  const float* cb   = (const float*)d_in[15];

  float* out = (float*)d_out;
  float* f   = (float*)d_ws;

  // ws layout (floats). ~119 MB total.
  float* slotA  = f;                       // h1: [64][2050][64]   8,396,800
  float* slotB1 = f + 8396800;             // h2 then h5: [64][1026][128]
  float* slotB2 = f + 16801792;            // h3 then h7
  float* slotC  = f + 25206784;            // h4 then h6: [64][1026][64]
  float* Wcf    = f + 29409280;            // 8192
  float* bc     = f + 29417472;            // 64
  float* cnorm  = f + 29417536;            // 512
  int*   counts = (int*)(f + 29418048);    // 512
  float* lossa  = f + 29418560;            // 1 (memset together w/ counts)
  short* AB     = (short*)(f + 29418576);  // 516096 shorts
  short* A1 = AB;                          // 49152
  short* A2 = AB + 49152;                  // 98304
  short* A3 = AB + 147456;                 // 147456
  short* A4 = AB + 294912;                 // 73728
  short* A5 = AB + 368640;                 // 24576
  short* A6 = AB + 393216;                 // 73728
  short* A7 = AB + 466944;                 // 24576
  short* A8 = AB + 491520;                 // 24576

  // output layout (floats): loss | z_q_st | perp | z_e | encodings | indices
  float* loss_out = out;
  float* zq_out   = out + 1;
  float* perp_out = out + 4194305;
  float* ze_out   = out + 4194306;
  float* enc_out  = out + 8388610;
  float* idx_out  = out + 41943042;

  prep_small<<<dim3(1), dim3(256), 0, stream>>>(wout, bout, wpq, bpq, cb,
                                                Wcf, bc, cnorm);
  prep_w_all<<<dim3(252), dim3(256), 0, stream>>>(w1, w2, w3, r0a, r0b, r1a,
                                                  r1b, Wcf,
                                                  A1, A2, A3, A4, A5, A6, A7, A8);
  zero_guards<<<dim3(32), dim3(256), 0, stream>>>(slotA, slotB1, slotB2, slotC);
  hipMemsetAsync(counts, 0, 2052, stream);

  // conv1: x (CHW) -> h1 (slotA)
  conv_mfma<64, 4, 2, false, true, false, true, false>
      <<<dim3(32, 64, 1), dim3(256), 0, stream>>>(x, A1, b1, nullptr, slotA,
                                                  4096, 2048, 4);
  // conv2: relu(h1) -> h2 (slotB1)
  conv_mfma<64, 4, 2, true, true, false, false, false>
      <<<dim3(16, 64, 2), dim3(256), 0, stream>>>(slotA, A2, b2, nullptr, slotB1,
                                                  2048, 1024, 8);
  // conv3: relu(h2) -> h3 (slotB2)
  conv_mfma<128, 3, 1, true, true, false, false, false>
      <<<dim3(16, 64, 2), dim3(256), 0, stream>>>(slotB1, A3, b3, nullptr, slotB2,
                                                  1024, 1024, 8);
  // r0a: relu(h3) -> h4 (slotC)
  conv_mfma<128, 3, 1, true, false, false, false, false>
      <<<dim3(16, 64, 1), dim3(256), 0, stream>>>(slotB2, A4, nullptr, nullptr,
                                                  slotC, 1024, 1024, 4);
  // r0b: relu(h4) + h3 -> h5 (slotB1)
  conv_mfma<64, 1, 1, true, false, true, false, false>
      <<<dim3(16, 64, 2), dim3(256), 0, stream>>>(slotC, A5, nullptr, slotB2,
                                                  slotB1, 1024, 1024, 8);
  // r1a: relu(h5) -> h6 (slotC)
  conv_mfma<128, 3, 1, true, false, false, false, false>
      <<<dim3(16, 64, 1), dim3(256), 0, stream>>>(slotB1, A6, nullptr, nullptr,
                                                  slotC, 1024, 1024, 4);
  // r1b: relu(h6) + h5 -> h7 (slotB2)
  conv_mfma<64, 1, 1, true, false, true, false, false>
      <<<dim3(16, 64, 2), dim3(256), 0, stream>>>(slotC, A7, nullptr, slotB1,
                                                  slotB2, 1024, 1024, 8);
  // final: relu(h7) x Wc + bc -> z_e (B,T,64) in d_out
  conv_mfma<128, 1, 1, true, true, false, false, true>
      <<<dim3(16, 64, 1), dim3(256), 0, stream>>>(slotB2, A8, bc, nullptr,
                                                  ze_out, 1024, 1024, 4);

  vq_k<<<dim3(512), dim3(256), 0, stream>>>(ze_out, cb, cnorm, zq_out, enc_out,
                                            idx_out, counts, lossa);
  fin_k<<<dim3(1), dim3(256), 0, stream>>>(counts, lossa, loss_out, perp_out);
}

// Round 6
// 698.189 us; speedup vs baseline: 1.8876x; 1.0588x over previous
//
#include <hip/hip_runtime.h>
#include <math.h>

// ---------------------------------------------------------------------------
// VQ-VAE encoder. Round 6: convs unchanged (r5, 3-term split-bf16 MFMA).
// VQ distance matrix moved onto MFMA too: val = z.c - |c|^2/2 accumulated by
// mfma_f32_16x16x32_bf16 with acc initialized to -cnorm/2; argmax == argmin
// of reference distance. z staged as 3-split bf16 B-frags in LDS (loaded
// once, reused across all 32 code-tiles); codebook pre-built as 3-split
// A-fragments in ws (L2-resident). Epilogue (enc/zq stores) unchanged.
// ---------------------------------------------------------------------------

typedef short short8 __attribute__((ext_vector_type(8)));
typedef float f32x4 __attribute__((ext_vector_type(4)));

__device__ __forceinline__ unsigned short bf16hi(float f) {
  unsigned u = __builtin_bit_cast(unsigned, f);
  return (unsigned short)((u + 0x7FFFu + ((u >> 16) & 1u)) >> 16);
}
__device__ __forceinline__ float bf16tof(unsigned short h) {
  unsigned u = ((unsigned)h) << 16;
  return __builtin_bit_cast(float, u);
}
__device__ __forceinline__ void split3(float f, unsigned short& h,
                                       unsigned short& m, unsigned short& l) {
  h = bf16hi(f);
  float r = f - bf16tof(h);
  m = bf16hi(r);
  l = bf16hi(r - bf16tof(m));
}

// ---------------------------------------------------------------------------
// conv kernel (unchanged from round 5)
// ---------------------------------------------------------------------------
template<int CIN, int TAPS, int S, bool RELU_IN, bool HAS_BIAS, bool RESID,
         bool CHW_IN, bool OUT_NOGUARD>
__global__ __launch_bounds__(256) void conv_mfma(
    const float* __restrict__ in, const short* __restrict__ Ab,
    const float* __restrict__ bias, const float* __restrict__ resid,
    float* __restrict__ out, int Tin, int Tout, int MTG)
{
  constexpr int nCk   = CIN / 32;
  constexpr int RS    = (S == 2) ? 130 : ((TAPS == 3) ? 66 : 64);
  constexpr int ROWBS = 40;

  __shared__ short xhi[RS * ROWBS];
  __shared__ short xmd[RS * ROWBS];
  __shared__ short xlo[RS * ROWBS];

  const int tid  = threadIdx.x;
  const int lane = tid & 63;
  const int wv   = tid >> 6;
  const int ih   = wv & 1;
  const int jh   = wv >> 1;
  const int tl   = lane & 15;
  const int q    = lane >> 4;
  const int b    = blockIdx.y;
  const int t0   = blockIdx.x * 64;
  const int co0  = blockIdx.z * 64;
  const int COUT = MTG * 16;

  const int rbase = (S == 2) ? (2 * t0) : ((TAPS == 3) ? t0 : (t0 + 1));

  f32x4 acc[2][2] = {};

  for (int ch = 0; ch < nCk; ch++) {
    if (ch) __syncthreads();

    if constexpr (!CHW_IN) {
      for (int i = tid; i < RS * 8; i += 256) {
        int rl = i >> 3;
        int c4 = (i & 7) * 4;
        int rg = rbase + rl;
        const float* sp = in + ((size_t)b * (Tin + 2) + rg) * CIN + ch * 32 + c4;
        float4 v = *(const float4*)sp;
        if (RELU_IN) {
          v.x = fmaxf(v.x, 0.f); v.y = fmaxf(v.y, 0.f);
          v.z = fmaxf(v.z, 0.f); v.w = fmaxf(v.w, 0.f);
        }
        float vv[4] = {v.x, v.y, v.z, v.w};
        unsigned short h[4], m[4], l[4];
        #pragma unroll
        for (int e = 0; e < 4; e++) split3(vv[e], h[e], m[e], l[e]);
        int slot = (S == 2) ? ((rl & 1) * 65 + (rl >> 1)) : rl;
        int off = slot * ROWBS + c4;
        uint2 uh, um, ul;
        uh.x = (unsigned)h[0] | ((unsigned)h[1] << 16);
        uh.y = (unsigned)h[2] | ((unsigned)h[3] << 16);
        um.x = (unsigned)m[0] | ((unsigned)m[1] << 16);
        um.y = (unsigned)m[2] | ((unsigned)m[3] << 16);
        ul.x = (unsigned)l[0] | ((unsigned)l[1] << 16);
        ul.y = (unsigned)l[2] | ((unsigned)l[3] << 16);
        *(uint2*)(xhi + off) = uh;
        *(uint2*)(xmd + off) = um;
        *(uint2*)(xlo + off) = ul;
      }
    } else {
      if (tid < 32) {
        int cig = ch * 32 + tid;
        int tin = 2 * t0 - 1;
        float v = 0.f;
        if (tin >= 0) v = in[((size_t)b * 64 + cig) * Tin + tin];
        unsigned short h, m, l;
        split3(v, h, m, l);
        xhi[tid] = (short)h;
        xmd[tid] = (short)m;
        xlo[tid] = (short)l;
      }
      int cil = tid >> 3, tq = tid & 7;
      for (int base = tq * 4; base <= 128; base += 32) {
        int tin0 = 2 * t0 + base;
        const float* sp = in + ((size_t)b * 64 + ch * 32 + cil) * Tin + tin0;
        float vv[4];
        if (tin0 + 3 < Tin) {
          float4 t4 = *(const float4*)sp;
          vv[0] = t4.x; vv[1] = t4.y; vv[2] = t4.z; vv[3] = t4.w;
        } else {
          #pragma unroll
          for (int e = 0; e < 4; e++) vv[e] = (tin0 + e < Tin) ? sp[e] : 0.f;
        }
        #pragma unroll
        for (int e = 0; e < 4; e++) {
          int rl = base + e + 1;
          if (rl <= 129) {
            unsigned short h, m, l;
            split3(vv[e], h, m, l);
            int slot = (rl & 1) * 65 + (rl >> 1);
            xhi[slot * ROWBS + cil] = (short)h;
            xmd[slot * ROWBS + cil] = (short)m;
            xlo[slot * ROWBS + cil] = (short)l;
          }
        }
      }
    }
    __syncthreads();

    #pragma unroll
    for (int tap = 0; tap < TAPS; tap++) {
      short8 ah[2], am[2], al[2];
      #pragma unroll
      for (int mi = 0; mi < 2; mi++) {
        const short* ab = Ab +
            (size_t)(((ch * TAPS + tap) * MTG + (co0 >> 4) + ih * 2 + mi) * 3) * 512
            + lane * 8;
        ah[mi] = *(const short8*)ab;
        am[mi] = *(const short8*)(ab + 512);
        al[mi] = *(const short8*)(ab + 1024);
      }
      #pragma unroll
      for (int nt = 0; nt < 2; nt++) {
        int tpos = jh * 32 + nt * 16 + tl;
        int slot;
        if constexpr (S == 2)         slot = (tap & 1) * 65 + tpos + (tap >> 1);
        else if constexpr (TAPS == 3) slot = tpos + tap;
        else                          slot = tpos;
        const int xo = slot * ROWBS + q * 8;
        short8 bh = *(const short8*)(xhi + xo);
        short8 bm = *(const short8*)(xmd + xo);
        short8 bl = *(const short8*)(xlo + xo);
        #pragma unroll
        for (int mi = 0; mi < 2; mi++) {
          acc[mi][nt] = __builtin_amdgcn_mfma_f32_16x16x32_bf16(ah[mi], bh, acc[mi][nt], 0, 0, 0);
          acc[mi][nt] = __builtin_amdgcn_mfma_f32_16x16x32_bf16(ah[mi], bm, acc[mi][nt], 0, 0, 0);
          acc[mi][nt] = __builtin_amdgcn_mfma_f32_16x16x32_bf16(am[mi], bh, acc[mi][nt], 0, 0, 0);
          acc[mi][nt] = __builtin_amdgcn_mfma_f32_16x16x32_bf16(am[mi], bm, acc[mi][nt], 0, 0, 0);
          acc[mi][nt] = __builtin_amdgcn_mfma_f32_16x16x32_bf16(ah[mi], bl, acc[mi][nt], 0, 0, 0);
          acc[mi][nt] = __builtin_amdgcn_mfma_f32_16x16x32_bf16(al[mi], bh, acc[mi][nt], 0, 0, 0);
        }
      }
    }
  }

  #pragma unroll
  for (int mi = 0; mi < 2; mi++) {
    #pragma unroll
    for (int nt = 0; nt < 2; nt++) {
      int t  = t0 + jh * 32 + nt * 16 + tl;
      int co = co0 + (ih * 2 + mi) * 16 + q * 4;
      f32x4 a = acc[mi][nt];
      float4 v = {a[0], a[1], a[2], a[3]};
      if constexpr (HAS_BIAS) {
        float4 bb = *(const float4*)(bias + co);
        v.x += bb.x; v.y += bb.y; v.z += bb.z; v.w += bb.w;
      }
      if constexpr (RESID) {
        float4 rr = *(const float4*)(resid + ((size_t)b * (Tout + 2) + t + 1) * COUT + co);
        v.x += rr.x; v.y += rr.y; v.z += rr.z; v.w += rr.w;
      }
      float* op;
      if constexpr (OUT_NOGUARD) op = out + ((size_t)b * Tout + t) * COUT + co;
      else                       op = out + ((size_t)b * (Tout + 2) + t + 1) * COUT + co;
      *(float4*)op = v;
    }
  }
}

// ---------------------------------------------------------------------------
// prep: Wc = wpq@w_out (fp32), bc, cnormd = -|c_k|^2/2
// ---------------------------------------------------------------------------
__global__ __launch_bounds__(256) void prep_small(
    const float* __restrict__ wout, const float* __restrict__ bout,
    const float* __restrict__ wpq, const float* __restrict__ bpq,
    const float* __restrict__ cb,
    float* __restrict__ Wc, float* __restrict__ bc, float* __restrict__ cnormd)
{
  const int tid = threadIdx.x;
  for (int i = tid; i < 64 * 128; i += 256) {
    int d = i >> 7, c = i & 127;
    float s = 0.f;
    for (int e = 0; e < 64; e++) s = fmaf(wpq[d * 64 + e], wout[e * 128 + c], s);
    Wc[i] = s;
  }
  for (int i = tid; i < 64; i += 256) {
    float s = bpq[i];
    for (int e = 0; e < 64; e++) s = fmaf(wpq[i * 64 + e], bout[e], s);
    bc[i] = s;
  }
  for (int k = tid; k < 512; k += 256) {
    float s = 0.f;
    for (int d = 0; d < 64; d++) { float c = cb[k * 64 + d]; s = fmaf(c, c, s); }
    cnormd[k] = -0.5f * s;
  }
}

// ---------------------------------------------------------------------------
// prep: conv A-fragments (unchanged) + codebook A-fragments for VQ
// ---------------------------------------------------------------------------
__device__ __forceinline__ void buildA(const float* w, short* dst,
                                       int COUT, int CIN, int TAPS, int idx)
{
  int lane = idx & 63;
  int rest = idx >> 6;
  int hl   = rest % 3;  rest /= 3;
  int mtg  = rest % (COUT / 16); rest /= (COUT / 16);
  int tap  = rest % TAPS;
  int chunk = rest / TAPS;
  int co  = mtg * 16 + (lane & 15);
  int ci0 = chunk * 32 + (lane >> 4) * 8;
  short v[8];
  #pragma unroll
  for (int j = 0; j < 8; j++) {
    float f = w[((size_t)co * CIN + ci0 + j) * TAPS + tap];
    unsigned short h, m, l;
    split3(f, h, m, l);
    v[j] = (hl == 0) ? (short)h : ((hl == 1) ? (short)m : (short)l);
  }
  int MTG = COUT / 16;
  size_t o = ((((size_t)(chunk * TAPS + tap) * MTG + mtg) * 3 + hl) * 64 + lane) * 8;
  #pragma unroll
  for (int j = 0; j < 8; j++) dst[o + j] = v[j];
}

__device__ __forceinline__ void buildAcb(const float* cb, short* dst, int g)
{
  int lane = g & 63;
  int rest = g >> 6;
  int s  = rest % 3; rest /= 3;
  int kc = rest & 1;
  int ct = rest >> 1;                      // 0..31
  int tl = lane & 15, q = lane >> 4;
  int code = ct * 16 + tl;
  int k0 = kc * 32 + q * 8;
  size_t o = (((size_t)(ct * 2 + kc) * 3 + s) * 64 + lane) * 8;
  #pragma unroll
  for (int j = 0; j < 8; j++) {
    float f = cb[(size_t)code * 64 + k0 + j];
    unsigned short h, m, l;
    split3(f, h, m, l);
    dst[o + j] = (s == 0) ? (short)h : ((s == 1) ? (short)m : (short)l);
  }
}

__global__ __launch_bounds__(256) void prep_w_all(
    const float* w1, const float* w2, const float* w3,
    const float* r0a, const float* r0b, const float* r1a, const float* r1b,
    const float* Wc, const float* cb,
    short* A1, short* A2, short* A3, short* A4, short* A5, short* A6,
    short* A7, short* A8, short* Acb)
{
  int g = blockIdx.x * 256 + threadIdx.x;
  if      (g < 6144)  buildA(w1,  A1, 64,  64,  4, g);
  else if (g < 18432) buildA(w2,  A2, 128, 64,  4, g - 6144);
  else if (g < 36864) buildA(w3,  A3, 128, 128, 3, g - 18432);
  else if (g < 46080) buildA(r0a, A4, 64,  128, 3, g - 36864);
  else if (g < 49152) buildA(r0b, A5, 128, 64,  1, g - 46080);
  else if (g < 58368) buildA(r1a, A6, 64,  128, 3, g - 49152);
  else if (g < 61440) buildA(r1b, A7, 128, 64,  1, g - 58368);
  else if (g < 64512) buildA(Wc,  A8, 64,  128, 1, g - 61440);
  else if (g < 76800) buildAcb(cb, Acb, g - 64512);
}

// ---- zero guard rows of the intermediate slots ---------------------------
__global__ __launch_bounds__(256) void zero_guards(
    float* __restrict__ sA, float* __restrict__ sB1,
    float* __restrict__ sB2, float* __restrict__ sC)
{
  int gt = blockIdx.x * 256 + threadIdx.x;
  int NT = gridDim.x * 256;
  for (int i = gt; i < 64 * 2 * 64; i += NT) {
    int b = i >> 7, r = (i >> 6) & 1, c = i & 63;
    sA[((size_t)b * 2050 + r * 2049) * 64 + c] = 0.f;
  }
  for (int i = gt; i < 64 * 2 * 128; i += NT) {
    int b = i >> 8, r = (i >> 7) & 1, c = i & 127;
    size_t o = ((size_t)b * 1026 + r * 1025) * 128 + c;
    sB1[o] = 0.f; sB2[o] = 0.f;
  }
  for (int i = gt; i < 64 * 2 * 64; i += NT) {
    int b = i >> 7, r = (i >> 6) & 1, c = i & 63;
    sC[((size_t)b * 1026 + r * 1025) * 64 + c] = 0.f;
  }
}

// ---------------------------------------------------------------------------
// VQ: 128 points/block. Distances via MFMA (acc init -cnorm/2, argmax).
// ---------------------------------------------------------------------------
__global__ __launch_bounds__(256) void vq_k(
    const float* __restrict__ ze, const float* __restrict__ cb,
    const float* __restrict__ cnormd, const short* __restrict__ Acb,
    float* __restrict__ zq_out, float* __restrict__ enc,
    float* __restrict__ idx_out,
    int* __restrict__ counts, float* __restrict__ loss_accum)
{
  __shared__ short zh[128 * 72];
  __shared__ short zm[128 * 72];
  __shared__ short zl[128 * 72];
  __shared__ int   idx_s[128];
  __shared__ float ls[4];

  const int tid  = threadIdx.x;
  const int lane = tid & 63;
  const int wv   = tid >> 6;
  const int tl   = lane & 15;
  const int q    = lane >> 4;
  const int n0   = blockIdx.x * 128;

  // ---- stage z as 3-split bf16, layout [point][72 shorts] ----
  {
    const float* zb = ze + (size_t)n0 * 64;
    #pragma unroll
    for (int j = 0; j < 8; j++) {
      int off = j * 1024 + tid * 4;
      int p = off >> 6, d = off & 63;
      float2 v0 = *(const float2*)(zb + off);
      float2 v1 = *(const float2*)(zb + off + 2);
      float vv[4] = {v0.x, v0.y, v1.x, v1.y};
      unsigned short h[4], m[4], l[4];
      #pragma unroll
      for (int e = 0; e < 4; e++) split3(vv[e], h[e], m[e], l[e]);
      int o = p * 72 + d;
      uint2 uh, um, ul;
      uh.x = (unsigned)h[0] | ((unsigned)h[1] << 16);
      uh.y = (unsigned)h[2] | ((unsigned)h[3] << 16);
      um.x = (unsigned)m[0] | ((unsigned)m[1] << 16);
      um.y = (unsigned)m[2] | ((unsigned)m[3] << 16);
      ul.x = (unsigned)l[0] | ((unsigned)l[1] << 16);
      ul.y = (unsigned)l[2] | ((unsigned)l[3] << 16);
      *(uint2*)(zh + o) = uh;
      *(uint2*)(zm + o) = um;
      *(uint2*)(zl + o) = ul;
    }
  }
  __syncthreads();

  // ---- B-frags for this wave's 2 point-tiles (reused for all code-tiles) --
  short8 bh[2][2], bm[2][2], bl[2][2];       // [pt][kc]
  #pragma unroll
  for (int pt = 0; pt < 2; pt++) {
    int row = wv * 32 + pt * 16 + tl;
    #pragma unroll
    for (int kc = 0; kc < 2; kc++) {
      int o = row * 72 + kc * 32 + q * 8;
      bh[pt][kc] = *(const short8*)(zh + o);
      bm[pt][kc] = *(const short8*)(zm + o);
      bl[pt][kc] = *(const short8*)(zl + o);
    }
  }

  float best0 = -3.4e38f, best1 = -3.4e38f;
  int   bi0 = 0, bi1 = 0;

  for (int ct = 0; ct < 32; ct++) {
    float4 cv = *(const float4*)(cnormd + ct * 16 + q * 4);
    f32x4 a0 = {cv.x, cv.y, cv.z, cv.w};
    f32x4 a1 = a0;
    #pragma unroll
    for (int kc = 0; kc < 2; kc++) {
      const short* ap = Acb + (size_t)((ct * 2 + kc) * 3) * 512 + lane * 8;
      short8 ah = *(const short8*)ap;
      short8 am = *(const short8*)(ap + 512);
      short8 al = *(const short8*)(ap + 1024);
      a0 = __builtin_amdgcn_mfma_f32_16x16x32_bf16(ah, bh[0][kc], a0, 0, 0, 0);
      a1 = __builtin_amdgcn_mfma_f32_16x16x32_bf16(ah, bh[1][kc], a1, 0, 0, 0);
      a0 = __builtin_amdgcn_mfma_f32_16x16x32_bf16(ah, bm[0][kc], a0, 0, 0, 0);
      a1 = __builtin_amdgcn_mfma_f32_16x16x32_bf16(ah, bm[1][kc], a1, 0, 0, 0);
      a0 = __builtin_amdgcn_mfma_f32_16x16x32_bf16(am, bh[0][kc], a0, 0, 0, 0);
      a1 = __builtin_amdgcn_mfma_f32_16x16x32_bf16(am, bh[1][kc], a1, 0, 0, 0);
      a0 = __builtin_amdgcn_mfma_f32_16x16x32_bf16(am, bm[0][kc], a0, 0, 0, 0);
      a1 = __builtin_amdgcn_mfma_f32_16x16x32_bf16(am, bm[1][kc], a1, 0, 0, 0);
      a0 = __builtin_amdgcn_mfma_f32_16x16x32_bf16(ah, bl[0][kc], a0, 0, 0, 0);
      a1 = __builtin_amdgcn_mfma_f32_16x16x32_bf16(ah, bl[1][kc], a1, 0, 0, 0);
      a0 = __builtin_amdgcn_mfma_f32_16x16x32_bf16(al, bh[0][kc], a0, 0, 0, 0);
      a1 = __builtin_amdgcn_mfma_f32_16x16x32_bf16(al, bh[1][kc], a1, 0, 0, 0);
    }
    #pragma unroll
    for (int r = 0; r < 4; r++) {
      int code = ct * 16 + q * 4 + r;       // ascending within lane
      float v0 = a0[r], v1 = a1[r];
      if (v0 > best0) { best0 = v0; bi0 = code; }
      if (v1 > best1) { best1 = v1; bi1 = code; }
    }
  }

  // ---- cross-quad butterfly argmax (tie -> lowest code) ----
  #pragma unroll
  for (int mask = 16; mask <= 32; mask <<= 1) {
    float v0 = __shfl_xor(best0, mask, 64); int i0 = __shfl_xor(bi0, mask, 64);
    float v1 = __shfl_xor(best1, mask, 64); int i1 = __shfl_xor(bi1, mask, 64);
    if (v0 > best0 || (v0 == best0 && i0 < bi0)) { best0 = v0; bi0 = i0; }
    if (v1 > best1 || (v1 == best1 && i1 < bi1)) { best1 = v1; bi1 = i1; }
  }
  if (q == 0) {
    int p0 = wv * 32 + tl;
    int p1 = p0 + 16;
    idx_s[p0] = bi0;
    idx_s[p1] = bi1;
    idx_out[n0 + p0] = (float)bi0;
    idx_out[n0 + p1] = (float)bi1;
    atomicAdd(&counts[bi0], 1);
    atomicAdd(&counts[bi1], 1);
  }
  __syncthreads();

  // ---- z_q gather + loss, linear coalesced ----
  float lsum = 0.f;
  const size_t obase = (size_t)n0 * 64;
  #pragma unroll
  for (int j = 0; j < 32; j++) {
    int pos = j * 256 + tid;
    int p = pos >> 6, d = pos & 63;
    int id = idx_s[p];
    float zq  = cb[id * 64 + d];
    float zev = ze[obase + pos];
    float df  = zq - zev;
    lsum = fmaf(df, df, lsum);
    zq_out[obase + pos] = zq;
  }
  #pragma unroll
  for (int off = 32; off; off >>= 1) lsum += __shfl_down(lsum, off, 64);
  if (lane == 0) ls[wv] = lsum;

  // ---- encodings one-hot rows, float4 stores ----
  for (int pp = 0; pp < 128; pp += 2) {
    int p   = pp + (tid >> 7);
    int col = (tid & 127) * 4;
    int id  = idx_s[p];
    float4 v;
    v.x = (col     == id) ? 1.0f : 0.0f;
    v.y = (col + 1 == id) ? 1.0f : 0.0f;
    v.z = (col + 2 == id) ? 1.0f : 0.0f;
    v.w = (col + 3 == id) ? 1.0f : 0.0f;
    *(float4*)(enc + (size_t)(n0 + p) * 512 + col) = v;
  }

  __syncthreads();
  if (tid == 0) atomicAdd(loss_accum, ls[0] + ls[1] + ls[2] + ls[3]);
}

__global__ __launch_bounds__(256) void fin_k(
    const int* __restrict__ counts, const float* __restrict__ loss_accum,
    float* __restrict__ loss_out, float* __restrict__ perp_out)
{
  __shared__ float sd[256];
  const int tid = threadIdx.x;
  float h = 0.f;
  for (int k = tid; k < 512; k += 256) {
    float em = (float)counts[k] * (1.0f / 65536.0f);
    h += em * logf(em + 1e-10f);
  }
  sd[tid] = h;
  __syncthreads();
  for (int s = 128; s; s >>= 1) {
    if (tid < s) sd[tid] += sd[tid + s];
    __syncthreads();
  }
  if (tid == 0) {
    *perp_out = expf(-sd[0]);
    *loss_out = *loss_accum * 1.25f / 4194304.f;
  }
}

// ---------------------------------------------------------------------------
extern "C" void kernel_launch(void* const* d_in, const int* in_sizes, int n_in,
                              void* d_out, int out_size, void* d_ws, size_t ws_size,
                              hipStream_t stream)
{
  const float* x    = (const float*)d_in[0];
  const float* w1   = (const float*)d_in[1];
  const float* b1   = (const float*)d_in[2];
  const float* w2   = (const float*)d_in[3];
  const float* b2   = (const float*)d_in[4];
  const float* w3   = (const float*)d_in[5];
  const float* b3   = (const float*)d_in[6];
  const float* r0a  = (const float*)d_in[7];
  const float* r0b  = (const float*)d_in[8];
  const float* r1a  = (const float*)d_in[9];
  const float* r1b  = (const float*)d_in[10];
  const float* wout = (const float*)d_in[11];
  const float* bout = (const float*)d_in[12];
  const float* wpq  = (const float*)d_in[13];
  const float* bpq  = (const float*)d_in[14];
  const float* cb   = (const float*)d_in[15];

  float* out = (float*)d_out;
  float* f   = (float*)d_ws;

  // ws layout (floats). ~119 MB total.
  float* slotA  = f;                       // h1: [64][2050][64]
  float* slotB1 = f + 8396800;             // h2 then h5: [64][1026][128]
  float* slotB2 = f + 16801792;            // h3 then h7
  float* slotC  = f + 25206784;            // h4 then h6: [64][1026][64]
  float* Wcf    = f + 29409280;            // 8192
  float* bc     = f + 29417472;            // 64
  float* cnormd = f + 29417536;            // 512
  int*   counts = (int*)(f + 29418048);    // 512
  float* lossa  = f + 29418560;            // 1
  short* AB     = (short*)(f + 29418576);  // 516096 shorts
  short* A1 = AB;
  short* A2 = AB + 49152;
  short* A3 = AB + 147456;
  short* A4 = AB + 294912;
  short* A5 = AB + 368640;
  short* A6 = AB + 393216;
  short* A7 = AB + 466944;
  short* A8 = AB + 491520;
  short* Acb = (short*)(f + 29676624);     // 98304 shorts (192 KB)

  // output layout (floats): loss | z_q_st | perp | z_e | encodings | indices
  float* loss_out = out;
  float* zq_out   = out + 1;
  float* perp_out = out + 4194305;
  float* ze_out   = out + 4194306;
  float* enc_out  = out + 8388610;
  float* idx_out  = out + 41943042;

  prep_small<<<dim3(1), dim3(256), 0, stream>>>(wout, bout, wpq, bpq, cb,
                                                Wcf, bc, cnormd);
  prep_w_all<<<dim3(300), dim3(256), 0, stream>>>(w1, w2, w3, r0a, r0b, r1a,
                                                  r1b, Wcf, cb,
                                                  A1, A2, A3, A4, A5, A6, A7,
                                                  A8, Acb);
  zero_guards<<<dim3(32), dim3(256), 0, stream>>>(slotA, slotB1, slotB2, slotC);
  hipMemsetAsync(counts, 0, 2052, stream);

  conv_mfma<64, 4, 2, false, true, false, true, false>
      <<<dim3(32, 64, 1), dim3(256), 0, stream>>>(x, A1, b1, nullptr, slotA,
                                                  4096, 2048, 4);
  conv_mfma<64, 4, 2, true, true, false, false, false>
      <<<dim3(16, 64, 2), dim3(256), 0, stream>>>(slotA, A2, b2, nullptr, slotB1,
                                                  2048, 1024, 8);
  conv_mfma<128, 3, 1, true, true, false, false, false>
      <<<dim3(16, 64, 2), dim3(256), 0, stream>>>(slotB1, A3, b3, nullptr, slotB2,
                                                  1024, 1024, 8);
  conv_mfma<128, 3, 1, true, false, false, false, false>
      <<<dim3(16, 64, 1), dim3(256), 0, stream>>>(slotB2, A4, nullptr, nullptr,
                                                  slotC, 1024, 1024, 4);
  conv_mfma<64, 1, 1, true, false, true, false, false>
      <<<dim3(16, 64, 2), dim3(256), 0, stream>>>(slotC, A5, nullptr, slotB2,
                                                  slotB1, 1024, 1024, 8);
  conv_mfma<128, 3, 1, true, false, false, false, false>
      <<<dim3(16, 64, 1), dim3(256), 0, stream>>>(slotB1, A6, nullptr, nullptr,
                                                  slotC, 1024, 1024, 4);
  conv_mfma<64, 1, 1, true, false, true, false, false>
      <<<dim3(16, 64, 2), dim3(256), 0, stream>>>(slotC, A7, nullptr, slotB1,
                                                  slotB2, 1024, 1024, 8);
  conv_mfma<128, 1, 1, true, true, false, false, true>
      <<<dim3(16, 64, 1), dim3(256), 0, stream>>>(slotB2, A8, bc, nullptr,
                                                  ze_out, 1024, 1024, 4);

  vq_k<<<dim3(512), dim3(256), 0, stream>>>(ze_out, cb, cnormd, Acb, zq_out,
                                            enc_out, idx_out, counts, lossa);
  fin_k<<<dim3(1), dim3(256), 0, stream>>>(counts, lossa, loss_out, perp_out);
}